// Round 16
// baseline (128.503 us; speedup 1.0000x reference)
//
#include <hip/hip_runtime.h>

typedef short bf16x8_t __attribute__((ext_vector_type(8)));
typedef float f32x4_t  __attribute__((ext_vector_type(4)));

#define MFMA16(a,b,c) __builtin_amdgcn_mfma_f32_16x16x32_bf16(a,b,c,0,0,0)

__device__ __forceinline__ unsigned short f2b(float x){
  unsigned u = __float_as_uint(x);
  u += 0x7fffu + ((u >> 16) & 1u);
  return (unsigned short)(u >> 16);
}

__device__ __forceinline__ void bar_lgkm(){
  asm volatile("s_waitcnt lgkmcnt(0)" ::: "memory");
  __builtin_amdgcn_s_barrier();
  __builtin_amdgcn_sched_barrier(0);
}

// ---------------- unified setup: zero out+denom (0..4095) | weights (4096..4351) | n_real (4352..4479) ----------------
__global__ void setup_k(const float* __restrict__ kw, const float* __restrict__ vw,
                        const int* __restrict__ mask,
                        float4* __restrict__ acc4, float4* __restrict__ den4,
                        unsigned short* __restrict__ wktb, unsigned short* __restrict__ wvb,
                        int* __restrict__ nreal){
  int bid = blockIdx.x, tid = threadIdx.x;
  if (bid < 4096){
    int i = bid * 256 + tid;                       // 0..1048575 float4 (= d_out)
    float4 z = {0.f, 0.f, 0.f, 0.f};
    acc4[i] = z;
    if (i < 4096) den4[i] = z;
  } else if (bid < 4352){
    int i = (bid - 4096) * 256 + tid;              // 0..65535
    int d = i >> 8, e = i & 255;
    wktb[i] = f2b(kw[e * 256 + d]);                // WkT[d][e] (transposed, for calc_qkp)
    wvb[i]  = f2b(vw[i]);                          // value_w as-is (for vproj_norm)
  } else {
    int b = (bid - 4352) * 4 + (tid >> 6), l = tid & 63;
    int s_ = 0;
    #pragma unroll
    for (int j = 0; j < 8; ++j) s_ += mask[(size_t)b * 512 + j * 64 + l];
    #pragma unroll
    for (int k = 1; k < 64; k <<= 1) s_ += __shfl_xor(s_, k);
    if (l == 0) nreal[b] = s_ < 1 ? 1 : (s_ > 512 ? 512 : s_);
  }
}

// ---------------- qs[b*32+q][e] = (queries[q,e] + context[b]@cond_w[q*256+e] + cond_b)*scale*inv_t ----------------
// 2048 blocks: (b-group of 8) x (q). cond_w rows are L2/L3-hot across b-groups.
__global__ __launch_bounds__(256) void calc_qs(
    const float* __restrict__ context, const float* __restrict__ queries,
    const float* __restrict__ logt, const float* __restrict__ condw,
    const float* __restrict__ condb, unsigned short* __restrict__ qs){
  __shared__ float ctx_l[8 * 64];
  int tid = threadIdx.x;
  int q   = blockIdx.x & 31;
  int b0  = (blockIdx.x >> 5) * 8;
  int qd  = q * 256 + tid;
  float4 cw[16];
  #pragma unroll
  for (int j = 0; j < 16; ++j) cw[j] = *(const float4*)(condw + (size_t)qd * 64 + 4 * j);
  float qbias = queries[qd] + condb[qd];
  float sc = 0.0625f * __expf(-logt[q >> 2]);      // scale * inv_temperature
  ctx_l[tid]       = context[(size_t)b0 * 64 + tid];
  ctx_l[tid + 256] = context[(size_t)b0 * 64 + tid + 256];
  __syncthreads();
  #pragma unroll
  for (int b = 0; b < 8; ++b){
    const float4* cl = (const float4*)(ctx_l + b * 64);
    float acc = 0.f;
    #pragma unroll
    for (int j = 0; j < 16; ++j){
      float4 cv = cl[j]; float4 w4 = cw[j];
      acc += cv.x * w4.x + cv.y * w4.y + cv.z * w4.z + cv.w * w4.w;
    }
    qs[((size_t)(b0 + b) * 32 + q) * 256 + tid] = f2b((qbias + acc) * sc);
  }
}

// ---------------- qkp[row][d] = sum_e qs[row][e] * key_w[e][d]   (row = b*32+q) ----------------
// 512 blocks x 32 rows: acc[2][4] (32 VGPR), 16 KB LDS -> ~6 blocks/CU (was 1 at 64 rows).
__global__ __launch_bounds__(256) void calc_qkp(
    const unsigned short* __restrict__ qs, const unsigned short* __restrict__ wkt,
    unsigned short* __restrict__ qkp){
  __shared__ unsigned short at[32 * 256];
  int tid = threadIdx.x, w = tid >> 6, l = tid & 63, h = l >> 4, c = l & 15;
  size_t r0 = (size_t)blockIdx.x * 32;
  #pragma unroll
  for (int j = 0; j < 4; ++j){
    int f = j * 2048 + tid * 8;
    int row = f >> 8, col = f & 255;
    bf16x8_t v = *(const bf16x8_t*)(qs + (r0 + row) * 256 + col);
    *(bf16x8_t*)&at[row * 256 + (col ^ ((row & 7) << 3))] = v;
  }
  __syncthreads();
  f32x4_t zero4 = {0.f, 0.f, 0.f, 0.f};
  f32x4_t acc[2][4];
  #pragma unroll
  for (int m = 0; m < 2; ++m)
    #pragma unroll
    for (int nt = 0; nt < 4; ++nt) acc[m][nt] = zero4;
  #pragma unroll
  for (int kk = 0; kk < 8; ++kk){
    bf16x8_t A[2];
    #pragma unroll
    for (int m = 0; m < 2; ++m){
      int row = c + 16 * m;
      A[m] = *(const bf16x8_t*)&at[row * 256 + ((kk * 32 + 8 * h) ^ ((row & 7) << 3))];
    }
    #pragma unroll
    for (int nt = 0; nt < 4; ++nt){
      int d = 64 * w + 16 * nt + c;
      bf16x8_t Bv = *(const bf16x8_t*)(wkt + (size_t)d * 256 + kk * 32 + 8 * h);
      #pragma unroll
      for (int m = 0; m < 2; ++m) acc[m][nt] = MFMA16(A[m], Bv, acc[m][nt]);
    }
  }
  #pragma unroll
  for (int m = 0; m < 2; ++m)
    #pragma unroll
    for (int nt = 0; nt < 4; ++nt)
      #pragma unroll
      for (int i = 0; i < 4; ++i){
        size_t row = r0 + 16 * m + 4 * h + i;
        int d = 64 * w + 16 * nt + c;
        qkp[row * 256 + d] = f2b(acc[m][nt][i]);
      }
}

// ---------------- partial attention over RAW keys: one block per (batch, 256-pos chunk) ----------------
// R15 golden: XCD pair-swizzle + streamed vT (VGPR < 128) + __launch_bounds__(256,4) -> 4 blocks/CU.
__global__ __launch_bounds__(256, 4) void attn_part(
    const float* __restrict__ keys, const int* __restrict__ nreal,
    const unsigned short* __restrict__ qkp,
    float* __restrict__ acc, float* __restrict__ deng){
  __shared__ unsigned short K[32 * 256];   // bf16 keys, swizzled, 16 KB
  __shared__ unsigned short vT[256 * 32];  // K^T [e][t], swizzled, 16 KB
  __shared__ unsigned short Pl[32 * 32];   // P [q][t] bf16, 2 KB
  __shared__ float denl[32];

  // XCD pair swizzle: both chunks of a batch stay on one XCD (R14 win)
  int lbid = (blockIdx.x & 7) * 128 + (blockIdx.x >> 3);
  int b = lbid >> 1, ch = lbid & 1;
  int n_real = nreal[b];
  int sbase = ch * 256;
  if (sbase >= n_real) return;                 // uniform early-exit, before any barrier

  int tid = threadIdx.x, w = tid >> 6, l = tid & 63, h = l >> 4, c = l & 15;
  int mt = w & 1, qt = w >> 1;
  if (tid < 32) denl[tid] = 0.f;

  // identity B-fragments for MFMA-transpose (exact for bf16 inputs)
  bf16x8_t bIe, bIo;
  #pragma unroll
  for (int j = 0; j < 8; ++j){
    bIe[j] = (h == (c >> 3)     && j == (c & 7)) ? (short)0x3F80 : (short)0;
    bIo[j] = (h == 2 + (c >> 3) && j == (c & 7)) ? (short)0x3F80 : (short)0;
  }

  // stage tile 0 into registers (8 x dwordx4 per lane; rows t = 4j + w, cols 4l..4l+3)
  const float* kptr = keys + ((size_t)b * 512 + sbase + w) * 256 + 4 * l;
  float4 R[8];
  #pragma unroll
  for (int j = 0; j < 8; ++j) R[j] = *(const float4*)(kptr + j * 1024);

  // this wave's qkp fragments (B-operand of logits MFMA)
  bf16x8_t qf[8];
  #pragma unroll
  for (int kk = 0; kk < 8; ++kk)
    qf[kk] = *(const bf16x8_t*)(qkp + ((size_t)b * 32 + 16 * qt + c) * 256 + kk * 32 + 8 * h);

  float slope0 = exp2f(-2.0f * (float)((c & 3) + 1));   // head = q&3

  f32x4_t zero4 = {0.f, 0.f, 0.f, 0.f};
  f32x4_t ao[2][4];
  #pragma unroll
  for (int q2 = 0; q2 < 2; ++q2)
    #pragma unroll
    for (int nt = 0; nt < 4; ++nt) ao[q2][nt] = zero4;

  int tend = (n_real - sbase + 31) >> 5; if (tend > 8) tend = 8;

  for (int it = 0; it < tend; ++it){
    int s0 = sbase + it * 32;
    // ---- convert R -> K (bf16, swizzled); interleave issue of next tile's loads ----
    const float* knext = kptr + (size_t)(it + 1) * (32 * 256);
    #pragma unroll
    for (int j = 0; j < 8; ++j){
      int row = 4 * j + w;
      int d4 = 4 * l;
      float4 kv = R[j];
      if (it + 1 < tend) R[j] = *(const float4*)(knext + j * 1024);
      uint2 p;
      p.x = (unsigned)f2b(kv.x) | ((unsigned)f2b(kv.y) << 16);
      p.y = (unsigned)f2b(kv.z) | ((unsigned)f2b(kv.w) << 16);
      *(uint2*)&K[row * 256 + (d4 ^ ((row & 7) << 3))] = p;
    }
    bar_lgkm();                          // BAR1: K visible; staging loads stay in flight

    // ---- logits + K^T (identity MFMA), K^T streamed straight to vT (low reg pressure) ----
    f32x4_t as_ = zero4;
    #pragma unroll
    for (int kk = 0; kk < 8; ++kk){
      int colk = kk * 32 + 8 * h;
      bf16x8_t A0 = *(const bf16x8_t*)&K[c * 256 + (colk ^ ((c & 7) << 3))];
      bf16x8_t A1 = *(const bf16x8_t*)&K[(c + 16) * 256 + (colk ^ ((c & 7) << 3))];
      as_ = MFMA16(mt ? A1 : A0, qf[kk], as_);
      if ((kk >> 1) == w){               // this wave's e-range: cols 64w..64w+63 (kk = 2w, 2w+1)
        int ntb = (kk & 1) << 1;
        f32x4_t tA = MFMA16(A0, bIe, zero4);   // m=0, nt=ntb
        f32x4_t tB = MFMA16(A0, bIo, zero4);   // m=0, nt=ntb+1
        f32x4_t tC = MFMA16(A1, bIe, zero4);   // m=1, nt=ntb
        f32x4_t tD = MFMA16(A1, bIo, zero4);   // m=1, nt=ntb+1
        int e0 = 64 * w + 16 * ntb + c;
        int e1 = e0 + 16;
        uint2 p;
        p.x = (unsigned)f2b(tA[0]) | ((unsigned)f2b(tA[1]) << 16);
        p.y = (unsigned)f2b(tA[2]) | ((unsigned)f2b(tA[3]) << 16);
        *(uint2*)&vT[e0 * 32 + ((4 * h) ^ ((e0 & 1) << 3))] = p;
        p.x = (unsigned)f2b(tB[0]) | ((unsigned)f2b(tB[1]) << 16);
        p.y = (unsigned)f2b(tB[2]) | ((unsigned)f2b(tB[3]) << 16);
        *(uint2*)&vT[e1 * 32 + ((4 * h) ^ ((e1 & 1) << 3))] = p;
        p.x = (unsigned)f2b(tC[0]) | ((unsigned)f2b(tC[1]) << 16);
        p.y = (unsigned)f2b(tC[2]) | ((unsigned)f2b(tC[3]) << 16);
        *(uint2*)&vT[e0 * 32 + ((16 + 4 * h) ^ ((e0 & 1) << 3))] = p;
        p.x = (unsigned)f2b(tD[0]) | ((unsigned)f2b(tD[1]) << 16);
        p.y = (unsigned)f2b(tD[2]) | ((unsigned)f2b(tD[3]) << 16);
        *(uint2*)&vT[e1 * 32 + ((16 + 4 * h) ^ ((e1 & 1) << 3))] = p;
      }
    }

    // ---- softmax (fixed-max): P = exp(logit - slope*games_ago), masked -> 0 ----
    {
      float e_[4]; float qs_ = 0.f;
      #pragma unroll
      for (int i = 0; i < 4; ++i){
        int s = s0 + 16 * mt + 4 * h + i;
        float ga = (float)(n_real - 1 - s);
        bool valid = (s < n_real);
        float v = valid ? __expf(as_[i] - slope0 * ga) : 0.f;
        e_[i] = v; qs_ += v;
      }
      float r = qs_ + __shfl_xor(qs_, 16); r += __shfl_xor(r, 32);
      if (l < 16) atomicAdd(&denl[16 * qt + c], r);
      int q = 16 * qt + c;
      int t0 = 16 * mt + 4 * h;
      uint2 p;
      p.x = (unsigned)f2b(e_[0]) | ((unsigned)f2b(e_[1]) << 16);
      p.y = (unsigned)f2b(e_[2]) | ((unsigned)f2b(e_[3]) << 16);
      *(uint2*)&Pl[q * 32 + (t0 ^ ((q & 1) << 3))] = p;
    }
    bar_lgkm();                          // BAR2: vT/Pl visible; K consumed

    // ---- PV over raw keys: ao[q][e] += P[q][t] * K[t][e] ----
    {
      bf16x8_t Ap0 = *(const bf16x8_t*)&Pl[c * 32 + ((8 * h) ^ ((c & 1) << 3))];
      bf16x8_t Ap1 = *(const bf16x8_t*)&Pl[(16 + c) * 32 + ((8 * h) ^ ((c & 1) << 3))];
      #pragma unroll
      for (int nt = 0; nt < 4; ++nt){
        int e = 64 * w + 16 * nt + c;
        bf16x8_t Bv = *(const bf16x8_t*)&vT[e * 32 + ((8 * h) ^ ((e & 1) << 3))];
        ao[0][nt] = MFMA16(Ap0, Bv, ao[0][nt]);
        ao[1][nt] = MFMA16(Ap1, Bv, ao[1][nt]);
      }
    }
  }

  // ---- accumulate partial numerators / denominators (XCD-local lines after swizzle) ----
  #pragma unroll
  for (int q2 = 0; q2 < 2; ++q2)
    #pragma unroll
    for (int nt = 0; nt < 4; ++nt){
      int e = 64 * w + 16 * nt + c;
      #pragma unroll
      for (int i = 0; i < 4; ++i){
        int q = 16 * q2 + 4 * h + i;
        atomicAdd(&acc[((size_t)b * 32 + q) * 256 + e], ao[q2][nt][i]);
      }
    }
  if (tid < 32) atomicAdd(&deng[b * 32 + tid], denl[tid]);
}

// ---------------- epilogue (IN-PLACE on d_out): out[row][e'] = sum_d (out[row][d]/den[row]) * value_w[e'][d] ----------------
// 512 blocks x 32 rows: a2[2][4] (32 VGPR), 16 KB LDS -> high TLP (was 1 block/CU at 64 rows).
__global__ __launch_bounds__(256) void vproj_norm(
    const float* __restrict__ deng, const unsigned short* __restrict__ wvb,
    float* __restrict__ out){
  __shared__ unsigned short at[32 * 256];
  __shared__ float dl[32];
  int tid = threadIdx.x, w = tid >> 6, l = tid & 63, h = l >> 4, c = l & 15;
  size_t r0 = (size_t)blockIdx.x * 32;
  if (tid < 32) dl[tid] = 1.f / deng[r0 + tid];
  __syncthreads();
  #pragma unroll
  for (int j = 0; j < 8; ++j){
    int idx = j * 256 + tid;                     // 0..2047 float4s = 32 rows x 64
    int row = idx >> 6, c4 = (idx & 63) * 4;
    f32x4_t v = *(const f32x4_t*)(out + (r0 + row) * 256 + c4);
    float iv = dl[row];
    uint2 p;
    p.x = (unsigned)f2b(v[0] * iv) | ((unsigned)f2b(v[1] * iv) << 16);
    p.y = (unsigned)f2b(v[2] * iv) | ((unsigned)f2b(v[3] * iv) << 16);
    *(uint2*)&at[row * 256 + (c4 ^ ((row & 7) << 3))] = p;
  }
  __syncthreads();
  f32x4_t zero4 = {0.f, 0.f, 0.f, 0.f};
  f32x4_t a2[2][4];
  #pragma unroll
  for (int m = 0; m < 2; ++m)
    #pragma unroll
    for (int nt = 0; nt < 4; ++nt) a2[m][nt] = zero4;
  #pragma unroll
  for (int kk = 0; kk < 8; ++kk){
    bf16x8_t A[2];
    #pragma unroll
    for (int m = 0; m < 2; ++m){
      int row = c + 16 * m;
      A[m] = *(const bf16x8_t*)&at[row * 256 + ((kk * 32 + 8 * h) ^ ((row & 7) << 3))];
    }
    #pragma unroll
    for (int nt = 0; nt < 4; ++nt){
      int ep = 64 * w + 16 * nt + c;
      bf16x8_t Bv = *(const bf16x8_t*)(wvb + (size_t)ep * 256 + kk * 32 + 8 * h);
      #pragma unroll
      for (int m = 0; m < 2; ++m) a2[m][nt] = MFMA16(A[m], Bv, a2[m][nt]);
    }
  }
  #pragma unroll
  for (int m = 0; m < 2; ++m)
    #pragma unroll
    for (int nt = 0; nt < 4; ++nt)
      #pragma unroll
      for (int i = 0; i < 4; ++i){
        size_t row = r0 + 16 * m + 4 * h + i;
        int ep = 64 * w + 16 * nt + c;
        out[row * 256 + ep] = a2[m][nt][i];
      }
}

extern "C" void kernel_launch(void* const* d_in, const int* in_sizes, int n_in,
                              void* d_out, int out_size, void* d_ws, size_t ws_size,
                              hipStream_t stream){
  const float* keys    = (const float*)d_in[0];
  const int*   mask    = (const int*)d_in[1];
  const float* context = (const float*)d_in[2];
  const float* queries = (const float*)d_in[3];
  const float* key_w   = (const float*)d_in[4];
  const float* value_w = (const float*)d_in[5];
  const float* logt    = (const float*)d_in[6];
  const float* cond_w  = (const float*)d_in[7];
  const float* cond_b  = (const float*)d_in[8];
  float* out = (float*)d_out;

  unsigned short* wkt = (unsigned short*)d_ws;           // 65536 bf16
  unsigned short* wvb = wkt + 65536;                     // 65536 bf16
  unsigned short* qs  = wvb + 65536;                     // 16384*256 bf16
  unsigned short* qkp = qs + (size_t)16384 * 256;        // 16384*256 bf16
  float* deng = (float*)(qkp + (size_t)16384 * 256);     // 16384 f32
  int*   nreal = (int*)(deng + 16384);                   // 512 int

  hipLaunchKernelGGL(setup_k,  dim3(4480), dim3(256), 0, stream, key_w, value_w, mask,
                     (float4*)out, (float4*)deng, wkt, wvb, nreal);
  hipLaunchKernelGGL(calc_qs,  dim3(2048), dim3(256), 0, stream, context, queries, logt, cond_w, cond_b, qs);
  hipLaunchKernelGGL(calc_qkp, dim3(512), dim3(256), 0, stream, qs, wkt, qkp);
  hipLaunchKernelGGL(attn_part, dim3(1024), dim3(256), 0, stream, keys, nreal, qkp, out, deng);
  hipLaunchKernelGGL(vproj_norm, dim3(512), dim3(256), 0, stream, deng, wvb, out);
}

// Round 17
// 126.585 us; speedup vs baseline: 1.0151x; 1.0151x over previous
//
#include <hip/hip_runtime.h>

typedef short bf16x8_t __attribute__((ext_vector_type(8)));
typedef float f32x4_t  __attribute__((ext_vector_type(4)));

#define MFMA16(a,b,c) __builtin_amdgcn_mfma_f32_16x16x32_bf16(a,b,c,0,0,0)

__device__ __forceinline__ unsigned short f2b(float x){
  unsigned u = __float_as_uint(x);
  u += 0x7fffu + ((u >> 16) & 1u);
  return (unsigned short)(u >> 16);
}

__device__ __forceinline__ void bar_lgkm(){
  asm volatile("s_waitcnt lgkmcnt(0)" ::: "memory");
  __builtin_amdgcn_s_barrier();
  __builtin_amdgcn_sched_barrier(0);
}

// ---------------- unified setup: zero out+denom (0..4095) | weights (4096..4351) | n_real (4352..4479) ----------------
__global__ void setup_k(const float* __restrict__ kw, const float* __restrict__ vw,
                        const int* __restrict__ mask,
                        float4* __restrict__ acc4, float4* __restrict__ den4,
                        unsigned short* __restrict__ wktb, unsigned short* __restrict__ wvb,
                        int* __restrict__ nreal){
  int bid = blockIdx.x, tid = threadIdx.x;
  if (bid < 4096){
    int i = bid * 256 + tid;                       // 0..1048575 float4 (= d_out)
    float4 z = {0.f, 0.f, 0.f, 0.f};
    acc4[i] = z;
    if (i < 4096) den4[i] = z;
  } else if (bid < 4352){
    int i = (bid - 4096) * 256 + tid;              // 0..65535
    int d = i >> 8, e = i & 255;
    wktb[i] = f2b(kw[e * 256 + d]);                // WkT[d][e] (transposed, for calc_qkp)
    wvb[i]  = f2b(vw[i]);                          // value_w as-is (for vproj_norm)
  } else {
    int b = (bid - 4352) * 4 + (tid >> 6), l = tid & 63;
    int s_ = 0;
    #pragma unroll
    for (int j = 0; j < 8; ++j) s_ += mask[(size_t)b * 512 + j * 64 + l];
    #pragma unroll
    for (int k = 1; k < 64; k <<= 1) s_ += __shfl_xor(s_, k);
    if (l == 0) nreal[b] = s_ < 1 ? 1 : (s_ > 512 ? 512 : s_);
  }
}

// ---------------- qs[b*32+q][e] = (queries[q,e] + context[b]@cond_w[q*256+e] + cond_b)*scale*inv_t ----------------
__global__ __launch_bounds__(256) void calc_qs(
    const float* __restrict__ context, const float* __restrict__ queries,
    const float* __restrict__ logt, const float* __restrict__ condw,
    const float* __restrict__ condb, unsigned short* __restrict__ qs){
  __shared__ float ctx_l[8 * 64];
  int tid = threadIdx.x;
  int q   = blockIdx.x & 31;
  int b0  = (blockIdx.x >> 5) * 8;
  int qd  = q * 256 + tid;
  float4 cw[16];
  #pragma unroll
  for (int j = 0; j < 16; ++j) cw[j] = *(const float4*)(condw + (size_t)qd * 64 + 4 * j);
  float qbias = queries[qd] + condb[qd];
  float sc = 0.0625f * __expf(-logt[q >> 2]);      // scale * inv_temperature
  ctx_l[tid]       = context[(size_t)b0 * 64 + tid];
  ctx_l[tid + 256] = context[(size_t)b0 * 64 + tid + 256];
  __syncthreads();
  #pragma unroll
  for (int b = 0; b < 8; ++b){
    const float4* cl = (const float4*)(ctx_l + b * 64);
    float acc = 0.f;
    #pragma unroll
    for (int j = 0; j < 16; ++j){
      float4 cv = cl[j]; float4 w4 = cw[j];
      acc += cv.x * w4.x + cv.y * w4.y + cv.z * w4.z + cv.w * w4.w;
    }
    qs[((size_t)(b0 + b) * 32 + q) * 256 + tid] = f2b((qbias + acc) * sc);
  }
}

// ---------------- qkp[row][d] = sum_e qs[row][e] * key_w[e][d]   (row = b*32+q)  [R15 shape] ----------------
__global__ __launch_bounds__(256) void calc_qkp(
    const unsigned short* __restrict__ qs, const unsigned short* __restrict__ wkt,
    unsigned short* __restrict__ qkp){
  __shared__ unsigned short at[64 * 256];
  int tid = threadIdx.x, w = tid >> 6, l = tid & 63, h = l >> 4, c = l & 15;
  size_t r0 = (size_t)blockIdx.x * 64;
  #pragma unroll
  for (int j = 0; j < 8; ++j){
    int f = j * 256 + tid;
    int row = f >> 5, col = (f & 31) * 8;
    bf16x8_t v = *(const bf16x8_t*)(qs + (r0 + row) * 256 + col);
    *(bf16x8_t*)&at[row * 256 + (col ^ ((row & 7) << 3))] = v;
  }
  __syncthreads();
  f32x4_t zero4 = {0.f, 0.f, 0.f, 0.f};
  f32x4_t acc[4][4];
  #pragma unroll
  for (int mt = 0; mt < 4; ++mt)
    #pragma unroll
    for (int nt = 0; nt < 4; ++nt) acc[mt][nt] = zero4;
  #pragma unroll
  for (int kk = 0; kk < 8; ++kk){
    bf16x8_t A[4];
    #pragma unroll
    for (int mt = 0; mt < 4; ++mt){
      int row = c + 16 * mt;
      A[mt] = *(const bf16x8_t*)&at[row * 256 + ((kk * 32 + 8 * h) ^ ((row & 7) << 3))];
    }
    #pragma unroll
    for (int nt = 0; nt < 4; ++nt){
      int d = 64 * w + 16 * nt + c;
      bf16x8_t Bv = *(const bf16x8_t*)(wkt + (size_t)d * 256 + kk * 32 + 8 * h);
      #pragma unroll
      for (int mt = 0; mt < 4; ++mt) acc[mt][nt] = MFMA16(A[mt], Bv, acc[mt][nt]);
    }
  }
  #pragma unroll
  for (int mt = 0; mt < 4; ++mt)
    #pragma unroll
    for (int nt = 0; nt < 4; ++nt)
      #pragma unroll
      for (int i = 0; i < 4; ++i){
        size_t row = r0 + 16 * mt + 4 * h + i;
        int d = 64 * w + 16 * nt + c;
        qkp[row * 256 + d] = f2b(acc[mt][nt][i]);
      }
}

// ---------------- partial attention over RAW keys: one block per (batch, 128-pos chunk) ----------------
// R15 golden inner loop. Single delta: chunk 256->128 (2048 blocks) to fill all 1024 resident
// slots (active blocks ~770 -> ~1280) and halve the straggler chain. XCD swizzle adapted.
__global__ __launch_bounds__(256, 4) void attn_part(
    const float* __restrict__ keys, const int* __restrict__ nreal,
    const unsigned short* __restrict__ qkp,
    float* __restrict__ acc, float* __restrict__ deng){
  __shared__ unsigned short K[32 * 256];   // bf16 keys, swizzled, 16 KB
  __shared__ unsigned short vT[256 * 32];  // K^T [e][t], swizzled, 16 KB
  __shared__ unsigned short Pl[32 * 32];   // P [q][t] bf16, 2 KB
  __shared__ float denl[32];

  // XCD swizzle: 2048 = 8 x 256; all 4 chunks of a batch contiguous -> same XCD
  int lbid = (blockIdx.x & 7) * 256 + (blockIdx.x >> 3);
  int b = lbid >> 2, ch = lbid & 3;
  int n_real = nreal[b];
  int sbase = ch * 128;
  if (sbase >= n_real) return;                 // uniform early-exit, before any barrier

  int tid = threadIdx.x, w = tid >> 6, l = tid & 63, h = l >> 4, c = l & 15;
  int mt = w & 1, qt = w >> 1;
  if (tid < 32) denl[tid] = 0.f;

  // identity B-fragments for MFMA-transpose (exact for bf16 inputs)
  bf16x8_t bIe, bIo;
  #pragma unroll
  for (int j = 0; j < 8; ++j){
    bIe[j] = (h == (c >> 3)     && j == (c & 7)) ? (short)0x3F80 : (short)0;
    bIo[j] = (h == 2 + (c >> 3) && j == (c & 7)) ? (short)0x3F80 : (short)0;
  }

  // stage tile 0 into registers (8 x dwordx4 per lane; rows t = 4j + w, cols 4l..4l+3)
  const float* kptr = keys + ((size_t)b * 512 + sbase + w) * 256 + 4 * l;
  float4 R[8];
  #pragma unroll
  for (int j = 0; j < 8; ++j) R[j] = *(const float4*)(kptr + j * 1024);

  // this wave's qkp fragments (B-operand of logits MFMA)
  bf16x8_t qf[8];
  #pragma unroll
  for (int kk = 0; kk < 8; ++kk)
    qf[kk] = *(const bf16x8_t*)(qkp + ((size_t)b * 32 + 16 * qt + c) * 256 + kk * 32 + 8 * h);

  float slope0 = exp2f(-2.0f * (float)((c & 3) + 1));   // head = q&3

  f32x4_t zero4 = {0.f, 0.f, 0.f, 0.f};
  f32x4_t ao[2][4];
  #pragma unroll
  for (int q2 = 0; q2 < 2; ++q2)
    #pragma unroll
    for (int nt = 0; nt < 4; ++nt) ao[q2][nt] = zero4;

  int tend = (n_real - sbase + 31) >> 5; if (tend > 4) tend = 4;

  for (int it = 0; it < tend; ++it){
    int s0 = sbase + it * 32;
    // ---- convert R -> K (bf16, swizzled); interleave issue of next tile's loads ----
    const float* knext = kptr + (size_t)(it + 1) * (32 * 256);
    #pragma unroll
    for (int j = 0; j < 8; ++j){
      int row = 4 * j + w;
      int d4 = 4 * l;
      float4 kv = R[j];
      if (it + 1 < tend) R[j] = *(const float4*)(knext + j * 1024);
      uint2 p;
      p.x = (unsigned)f2b(kv.x) | ((unsigned)f2b(kv.y) << 16);
      p.y = (unsigned)f2b(kv.z) | ((unsigned)f2b(kv.w) << 16);
      *(uint2*)&K[row * 256 + (d4 ^ ((row & 7) << 3))] = p;
    }
    bar_lgkm();                          // BAR1: K visible; staging loads stay in flight

    // ---- logits + K^T (identity MFMA), K^T streamed straight to vT (low reg pressure) ----
    f32x4_t as_ = zero4;
    #pragma unroll
    for (int kk = 0; kk < 8; ++kk){
      int colk = kk * 32 + 8 * h;
      bf16x8_t A0 = *(const bf16x8_t*)&K[c * 256 + (colk ^ ((c & 7) << 3))];
      bf16x8_t A1 = *(const bf16x8_t*)&K[(c + 16) * 256 + (colk ^ ((c & 7) << 3))];
      as_ = MFMA16(mt ? A1 : A0, qf[kk], as_);
      if ((kk >> 1) == w){               // this wave's e-range: cols 64w..64w+63 (kk = 2w, 2w+1)
        int ntb = (kk & 1) << 1;
        f32x4_t tA = MFMA16(A0, bIe, zero4);   // m=0, nt=ntb
        f32x4_t tB = MFMA16(A0, bIo, zero4);   // m=0, nt=ntb+1
        f32x4_t tC = MFMA16(A1, bIe, zero4);   // m=1, nt=ntb
        f32x4_t tD = MFMA16(A1, bIo, zero4);   // m=1, nt=ntb+1
        int e0 = 64 * w + 16 * ntb + c;
        int e1 = e0 + 16;
        uint2 p;
        p.x = (unsigned)f2b(tA[0]) | ((unsigned)f2b(tA[1]) << 16);
        p.y = (unsigned)f2b(tA[2]) | ((unsigned)f2b(tA[3]) << 16);
        *(uint2*)&vT[e0 * 32 + ((4 * h) ^ ((e0 & 1) << 3))] = p;
        p.x = (unsigned)f2b(tB[0]) | ((unsigned)f2b(tB[1]) << 16);
        p.y = (unsigned)f2b(tB[2]) | ((unsigned)f2b(tB[3]) << 16);
        *(uint2*)&vT[e1 * 32 + ((4 * h) ^ ((e1 & 1) << 3))] = p;
        p.x = (unsigned)f2b(tC[0]) | ((unsigned)f2b(tC[1]) << 16);
        p.y = (unsigned)f2b(tC[2]) | ((unsigned)f2b(tC[3]) << 16);
        *(uint2*)&vT[e0 * 32 + ((16 + 4 * h) ^ ((e0 & 1) << 3))] = p;
        p.x = (unsigned)f2b(tD[0]) | ((unsigned)f2b(tD[1]) << 16);
        p.y = (unsigned)f2b(tD[2]) | ((unsigned)f2b(tD[3]) << 16);
        *(uint2*)&vT[e1 * 32 + ((16 + 4 * h) ^ ((e1 & 1) << 3))] = p;
      }
    }

    // ---- softmax (fixed-max): P = exp(logit - slope*games_ago), masked -> 0 ----
    {
      float e_[4]; float qs_ = 0.f;
      #pragma unroll
      for (int i = 0; i < 4; ++i){
        int s = s0 + 16 * mt + 4 * h + i;
        float ga = (float)(n_real - 1 - s);
        bool valid = (s < n_real);
        float v = valid ? __expf(as_[i] - slope0 * ga) : 0.f;
        e_[i] = v; qs_ += v;
      }
      float r = qs_ + __shfl_xor(qs_, 16); r += __shfl_xor(r, 32);
      if (l < 16) atomicAdd(&denl[16 * qt + c], r);
      int q = 16 * qt + c;
      int t0 = 16 * mt + 4 * h;
      uint2 p;
      p.x = (unsigned)f2b(e_[0]) | ((unsigned)f2b(e_[1]) << 16);
      p.y = (unsigned)f2b(e_[2]) | ((unsigned)f2b(e_[3]) << 16);
      *(uint2*)&Pl[q * 32 + (t0 ^ ((q & 1) << 3))] = p;
    }
    bar_lgkm();                          // BAR2: vT/Pl visible; K consumed

    // ---- PV over raw keys: ao[q][e] += P[q][t] * K[t][e] ----
    {
      bf16x8_t Ap0 = *(const bf16x8_t*)&Pl[c * 32 + ((8 * h) ^ ((c & 1) << 3))];
      bf16x8_t Ap1 = *(const bf16x8_t*)&Pl[(16 + c) * 32 + ((8 * h) ^ ((c & 1) << 3))];
      #pragma unroll
      for (int nt = 0; nt < 4; ++nt){
        int e = 64 * w + 16 * nt + c;
        bf16x8_t Bv = *(const bf16x8_t*)&vT[e * 32 + ((8 * h) ^ ((e & 1) << 3))];
        ao[0][nt] = MFMA16(Ap0, Bv, ao[0][nt]);
        ao[1][nt] = MFMA16(Ap1, Bv, ao[1][nt]);
      }
    }
  }

  // ---- accumulate partial numerators / denominators (XCD-local lines after swizzle) ----
  #pragma unroll
  for (int q2 = 0; q2 < 2; ++q2)
    #pragma unroll
    for (int nt = 0; nt < 4; ++nt){
      int e = 64 * w + 16 * nt + c;
      #pragma unroll
      for (int i = 0; i < 4; ++i){
        int q = 16 * q2 + 4 * h + i;
        atomicAdd(&acc[((size_t)b * 32 + q) * 256 + e], ao[q2][nt][i]);
      }
    }
  if (tid < 32) atomicAdd(&deng[b * 32 + tid], denl[tid]);
}

// ---------------- epilogue (IN-PLACE on d_out): out[row][e'] = sum_d (out[row][d]/den[row]) * value_w[e'][d]  [R15 shape] ----------------
__global__ __launch_bounds__(256) void vproj_norm(
    const float* __restrict__ deng, const unsigned short* __restrict__ wvb,
    float* __restrict__ out){
  __shared__ unsigned short at[64 * 256];
  __shared__ float dl[64];
  int tid = threadIdx.x, w = tid >> 6, l = tid & 63, h = l >> 4, c = l & 15;
  size_t r0 = (size_t)blockIdx.x * 64;
  if (tid < 64) dl[tid] = 1.f / deng[r0 + tid];
  __syncthreads();
  #pragma unroll
  for (int j = 0; j < 16; ++j){
    int idx = j * 256 + tid;
    int row = idx >> 6, c4 = (idx & 63) * 4;
    f32x4_t v = *(const f32x4_t*)(out + (r0 + row) * 256 + c4);
    float iv = dl[row];
    uint2 p;
    p.x = (unsigned)f2b(v[0] * iv) | ((unsigned)f2b(v[1] * iv) << 16);
    p.y = (unsigned)f2b(v[2] * iv) | ((unsigned)f2b(v[3] * iv) << 16);
    *(uint2*)&at[row * 256 + (c4 ^ ((row & 7) << 3))] = p;
  }
  __syncthreads();
  f32x4_t zero4 = {0.f, 0.f, 0.f, 0.f};
  f32x4_t a2[4][4];
  #pragma unroll
  for (int m = 0; m < 4; ++m)
    #pragma unroll
    for (int nt = 0; nt < 4; ++nt) a2[m][nt] = zero4;
  #pragma unroll
  for (int kk = 0; kk < 8; ++kk){
    bf16x8_t A[4];
    #pragma unroll
    for (int m = 0; m < 4; ++m){
      int row = c + 16 * m;
      A[m] = *(const bf16x8_t*)&at[row * 256 + ((kk * 32 + 8 * h) ^ ((row & 7) << 3))];
    }
    #pragma unroll
    for (int nt = 0; nt < 4; ++nt){
      int ep = 64 * w + 16 * nt + c;
      bf16x8_t Bv = *(const bf16x8_t*)(wvb + (size_t)ep * 256 + kk * 32 + 8 * h);
      #pragma unroll
      for (int m = 0; m < 4; ++m) a2[m][nt] = MFMA16(A[m], Bv, a2[m][nt]);
    }
  }
  #pragma unroll
  for (int m = 0; m < 4; ++m)
    #pragma unroll
    for (int nt = 0; nt < 4; ++nt)
      #pragma unroll
      for (int i = 0; i < 4; ++i){
        size_t row = r0 + 16 * m + 4 * h + i;
        int ep = 64 * w + 16 * nt + c;
        out[row * 256 + ep] = a2[m][nt][i];
      }
}

extern "C" void kernel_launch(void* const* d_in, const int* in_sizes, int n_in,
                              void* d_out, int out_size, void* d_ws, size_t ws_size,
                              hipStream_t stream){
  const float* keys    = (const float*)d_in[0];
  const int*   mask    = (const int*)d_in[1];
  const float* context = (const float*)d_in[2];
  const float* queries = (const float*)d_in[3];
  const float* key_w   = (const float*)d_in[4];
  const float* value_w = (const float*)d_in[5];
  const float* logt    = (const float*)d_in[6];
  const float* cond_w  = (const float*)d_in[7];
  const float* cond_b  = (const float*)d_in[8];
  float* out = (float*)d_out;

  unsigned short* wkt = (unsigned short*)d_ws;           // 65536 bf16
  unsigned short* wvb = wkt + 65536;                     // 65536 bf16
  unsigned short* qs  = wvb + 65536;                     // 16384*256 bf16
  unsigned short* qkp = qs + (size_t)16384 * 256;        // 16384*256 bf16
  float* deng = (float*)(qkp + (size_t)16384 * 256);     // 16384 f32
  int*   nreal = (int*)(deng + 16384);                   // 512 int

  hipLaunchKernelGGL(setup_k,  dim3(4480), dim3(256), 0, stream, key_w, value_w, mask,
                     (float4*)out, (float4*)deng, wkt, wvb, nreal);
  hipLaunchKernelGGL(calc_qs,  dim3(2048), dim3(256), 0, stream, context, queries, logt, cond_w, cond_b, qs);
  hipLaunchKernelGGL(calc_qkp, dim3(256), dim3(256), 0, stream, qs, wkt, qkp);
  hipLaunchKernelGGL(attn_part, dim3(2048), dim3(256), 0, stream, keys, nreal, qkp, out, deng);
  hipLaunchKernelGGL(vproj_norm, dim3(256), dim3(256), 0, stream, deng, wvb, out);
}

// Round 18
// 115.840 us; speedup vs baseline: 1.1093x; 1.0928x over previous
//
#include <hip/hip_runtime.h>

typedef short bf16x8_t __attribute__((ext_vector_type(8)));
typedef float f32x4_t  __attribute__((ext_vector_type(4)));

#define MFMA16(a,b,c) __builtin_amdgcn_mfma_f32_16x16x32_bf16(a,b,c,0,0,0)

__device__ __forceinline__ unsigned short f2b(float x){
  unsigned u = __float_as_uint(x);
  u += 0x7fffu + ((u >> 16) & 1u);
  return (unsigned short)(u >> 16);
}

__device__ __forceinline__ void bar_lgkm(){
  asm volatile("s_waitcnt lgkmcnt(0)" ::: "memory");
  __builtin_amdgcn_s_barrier();
  __builtin_amdgcn_sched_barrier(0);
}

// ---------------- unified setup: zero out+denom (0..4095) | weights (4096..4351) | n_real (4352..4479) ----------------
__global__ void setup_k(const float* __restrict__ kw, const float* __restrict__ vw,
                        const int* __restrict__ mask,
                        float4* __restrict__ acc4, float4* __restrict__ den4,
                        unsigned short* __restrict__ wktb, unsigned short* __restrict__ wvb,
                        int* __restrict__ nreal){
  int bid = blockIdx.x, tid = threadIdx.x;
  if (bid < 4096){
    int i = bid * 256 + tid;                       // 0..1048575 float4 (= d_out)
    float4 z = {0.f, 0.f, 0.f, 0.f};
    acc4[i] = z;
    if (i < 4096) den4[i] = z;
  } else if (bid < 4352){
    int i = (bid - 4096) * 256 + tid;              // 0..65535
    int d = i >> 8, e = i & 255;
    wktb[i] = f2b(kw[e * 256 + d]);                // WkT[d][e] (transposed, for calc_qkp)
    wvb[i]  = f2b(vw[i]);                          // value_w as-is (for vproj_norm)
  } else {
    int b = (bid - 4352) * 4 + (tid >> 6), l = tid & 63;
    int s_ = 0;
    #pragma unroll
    for (int j = 0; j < 8; ++j) s_ += mask[(size_t)b * 512 + j * 64 + l];
    #pragma unroll
    for (int k = 1; k < 64; k <<= 1) s_ += __shfl_xor(s_, k);
    if (l == 0) nreal[b] = s_ < 1 ? 1 : (s_ > 512 ? 512 : s_);
  }
}

// ---------------- qs[b*32+q][e] = (queries[q,e] + context[b]@cond_w[q*256+e] + cond_b)*scale*inv_t ----------------
__global__ __launch_bounds__(256) void calc_qs(
    const float* __restrict__ context, const float* __restrict__ queries,
    const float* __restrict__ logt, const float* __restrict__ condw,
    const float* __restrict__ condb, unsigned short* __restrict__ qs){
  __shared__ float ctx_l[8 * 64];
  int tid = threadIdx.x;
  int q   = blockIdx.x & 31;
  int b0  = (blockIdx.x >> 5) * 8;
  int qd  = q * 256 + tid;
  float4 cw[16];
  #pragma unroll
  for (int j = 0; j < 16; ++j) cw[j] = *(const float4*)(condw + (size_t)qd * 64 + 4 * j);
  float qbias = queries[qd] + condb[qd];
  float sc = 0.0625f * __expf(-logt[q >> 2]);      // scale * inv_temperature
  ctx_l[tid]       = context[(size_t)b0 * 64 + tid];
  ctx_l[tid + 256] = context[(size_t)b0 * 64 + tid + 256];
  __syncthreads();
  #pragma unroll
  for (int b = 0; b < 8; ++b){
    const float4* cl = (const float4*)(ctx_l + b * 64);
    float acc = 0.f;
    #pragma unroll
    for (int j = 0; j < 16; ++j){
      float4 cv = cl[j]; float4 w4 = cw[j];
      acc += cv.x * w4.x + cv.y * w4.y + cv.z * w4.z + cv.w * w4.w;
    }
    qs[((size_t)(b0 + b) * 32 + q) * 256 + tid] = f2b((qbias + acc) * sc);
  }
}

// ---------------- qkp[row][d] = sum_e qs[row][e] * key_w[e][d]   (row = b*32+q) ----------------
__global__ __launch_bounds__(256) void calc_qkp(
    const unsigned short* __restrict__ qs, const unsigned short* __restrict__ wkt,
    unsigned short* __restrict__ qkp){
  __shared__ unsigned short at[64 * 256];
  int tid = threadIdx.x, w = tid >> 6, l = tid & 63, h = l >> 4, c = l & 15;
  size_t r0 = (size_t)blockIdx.x * 64;
  #pragma unroll
  for (int j = 0; j < 8; ++j){
    int f = j * 256 + tid;
    int row = f >> 5, col = (f & 31) * 8;
    bf16x8_t v = *(const bf16x8_t*)(qs + (r0 + row) * 256 + col);
    *(bf16x8_t*)&at[row * 256 + (col ^ ((row & 7) << 3))] = v;
  }
  __syncthreads();
  f32x4_t zero4 = {0.f, 0.f, 0.f, 0.f};
  f32x4_t acc[4][4];
  #pragma unroll
  for (int mt = 0; mt < 4; ++mt)
    #pragma unroll
    for (int nt = 0; nt < 4; ++nt) acc[mt][nt] = zero4;
  #pragma unroll
  for (int kk = 0; kk < 8; ++kk){
    bf16x8_t A[4];
    #pragma unroll
    for (int mt = 0; mt < 4; ++mt){
      int row = c + 16 * mt;
      A[mt] = *(const bf16x8_t*)&at[row * 256 + ((kk * 32 + 8 * h) ^ ((row & 7) << 3))];
    }
    #pragma unroll
    for (int nt = 0; nt < 4; ++nt){
      int d = 64 * w + 16 * nt + c;
      bf16x8_t Bv = *(const bf16x8_t*)(wkt + (size_t)d * 256 + kk * 32 + 8 * h);
      #pragma unroll
      for (int mt = 0; mt < 4; ++mt) acc[mt][nt] = MFMA16(A[mt], Bv, acc[mt][nt]);
    }
  }
  #pragma unroll
  for (int mt = 0; mt < 4; ++mt)
    #pragma unroll
    for (int nt = 0; nt < 4; ++nt)
      #pragma unroll
      for (int i = 0; i < 4; ++i){
        size_t row = r0 + 16 * mt + 4 * h + i;
        int d = 64 * w + 16 * nt + c;
        qkp[row * 256 + d] = f2b(acc[mt][nt][i]);
      }
}

// ---------------- partial attention over RAW keys: one block per (batch, 256-pos chunk) ----------------
// R15 golden: XCD pair-swizzle + streamed vT (VGPR < 128) + __launch_bounds__(256,4) -> 4 blocks/CU.
__global__ __launch_bounds__(256, 4) void attn_part(
    const float* __restrict__ keys, const int* __restrict__ nreal,
    const unsigned short* __restrict__ qkp,
    float* __restrict__ acc, float* __restrict__ deng){
  __shared__ unsigned short K[32 * 256];   // bf16 keys, swizzled, 16 KB
  __shared__ unsigned short vT[256 * 32];  // K^T [e][t], swizzled, 16 KB
  __shared__ unsigned short Pl[32 * 32];   // P [q][t] bf16, 2 KB
  __shared__ float denl[32];

  // XCD pair swizzle: both chunks of a batch stay on one XCD (R14 win)
  int lbid = (blockIdx.x & 7) * 128 + (blockIdx.x >> 3);
  int b = lbid >> 1, ch = lbid & 1;
  int n_real = nreal[b];
  int sbase = ch * 256;
  if (sbase >= n_real) return;                 // uniform early-exit, before any barrier

  int tid = threadIdx.x, w = tid >> 6, l = tid & 63, h = l >> 4, c = l & 15;
  int mt = w & 1, qt = w >> 1;
  if (tid < 32) denl[tid] = 0.f;

  // identity B-fragments for MFMA-transpose (exact for bf16 inputs)
  bf16x8_t bIe, bIo;
  #pragma unroll
  for (int j = 0; j < 8; ++j){
    bIe[j] = (h == (c >> 3)     && j == (c & 7)) ? (short)0x3F80 : (short)0;
    bIo[j] = (h == 2 + (c >> 3) && j == (c & 7)) ? (short)0x3F80 : (short)0;
  }

  // stage tile 0 into registers (8 x dwordx4 per lane; rows t = 4j + w, cols 4l..4l+3)
  const float* kptr = keys + ((size_t)b * 512 + sbase + w) * 256 + 4 * l;
  float4 R[8];
  #pragma unroll
  for (int j = 0; j < 8; ++j) R[j] = *(const float4*)(kptr + j * 1024);

  // this wave's qkp fragments (B-operand of logits MFMA)
  bf16x8_t qf[8];
  #pragma unroll
  for (int kk = 0; kk < 8; ++kk)
    qf[kk] = *(const bf16x8_t*)(qkp + ((size_t)b * 32 + 16 * qt + c) * 256 + kk * 32 + 8 * h);

  float slope0 = exp2f(-2.0f * (float)((c & 3) + 1));   // head = q&3

  f32x4_t zero4 = {0.f, 0.f, 0.f, 0.f};
  f32x4_t ao[2][4];
  #pragma unroll
  for (int q2 = 0; q2 < 2; ++q2)
    #pragma unroll
    for (int nt = 0; nt < 4; ++nt) ao[q2][nt] = zero4;

  int tend = (n_real - sbase + 31) >> 5; if (tend > 8) tend = 8;

  for (int it = 0; it < tend; ++it){
    int s0 = sbase + it * 32;
    // ---- convert R -> K (bf16, swizzled); interleave issue of next tile's loads ----
    const float* knext = kptr + (size_t)(it + 1) * (32 * 256);
    #pragma unroll
    for (int j = 0; j < 8; ++j){
      int row = 4 * j + w;
      int d4 = 4 * l;
      float4 kv = R[j];
      if (it + 1 < tend) R[j] = *(const float4*)(knext + j * 1024);
      uint2 p;
      p.x = (unsigned)f2b(kv.x) | ((unsigned)f2b(kv.y) << 16);
      p.y = (unsigned)f2b(kv.z) | ((unsigned)f2b(kv.w) << 16);
      *(uint2*)&K[row * 256 + (d4 ^ ((row & 7) << 3))] = p;
    }
    bar_lgkm();                          // BAR1: K visible; staging loads stay in flight

    // ---- logits + K^T (identity MFMA), K^T streamed straight to vT (low reg pressure) ----
    f32x4_t as_ = zero4;
    #pragma unroll
    for (int kk = 0; kk < 8; ++kk){
      int colk = kk * 32 + 8 * h;
      bf16x8_t A0 = *(const bf16x8_t*)&K[c * 256 + (colk ^ ((c & 7) << 3))];
      bf16x8_t A1 = *(const bf16x8_t*)&K[(c + 16) * 256 + (colk ^ ((c & 7) << 3))];
      as_ = MFMA16(mt ? A1 : A0, qf[kk], as_);
      if ((kk >> 1) == w){               // this wave's e-range: cols 64w..64w+63 (kk = 2w, 2w+1)
        int ntb = (kk & 1) << 1;
        f32x4_t tA = MFMA16(A0, bIe, zero4);   // m=0, nt=ntb
        f32x4_t tB = MFMA16(A0, bIo, zero4);   // m=0, nt=ntb+1
        f32x4_t tC = MFMA16(A1, bIe, zero4);   // m=1, nt=ntb
        f32x4_t tD = MFMA16(A1, bIo, zero4);   // m=1, nt=ntb+1
        int e0 = 64 * w + 16 * ntb + c;
        int e1 = e0 + 16;
        uint2 p;
        p.x = (unsigned)f2b(tA[0]) | ((unsigned)f2b(tA[1]) << 16);
        p.y = (unsigned)f2b(tA[2]) | ((unsigned)f2b(tA[3]) << 16);
        *(uint2*)&vT[e0 * 32 + ((4 * h) ^ ((e0 & 1) << 3))] = p;
        p.x = (unsigned)f2b(tB[0]) | ((unsigned)f2b(tB[1]) << 16);
        p.y = (unsigned)f2b(tB[2]) | ((unsigned)f2b(tB[3]) << 16);
        *(uint2*)&vT[e1 * 32 + ((4 * h) ^ ((e1 & 1) << 3))] = p;
        p.x = (unsigned)f2b(tC[0]) | ((unsigned)f2b(tC[1]) << 16);
        p.y = (unsigned)f2b(tC[2]) | ((unsigned)f2b(tC[3]) << 16);
        *(uint2*)&vT[e0 * 32 + ((16 + 4 * h) ^ ((e0 & 1) << 3))] = p;
        p.x = (unsigned)f2b(tD[0]) | ((unsigned)f2b(tD[1]) << 16);
        p.y = (unsigned)f2b(tD[2]) | ((unsigned)f2b(tD[3]) << 16);
        *(uint2*)&vT[e1 * 32 + ((16 + 4 * h) ^ ((e1 & 1) << 3))] = p;
      }
    }

    // ---- softmax (fixed-max): P = exp(logit - slope*games_ago), masked -> 0 ----
    {
      float e_[4]; float qs_ = 0.f;
      #pragma unroll
      for (int i = 0; i < 4; ++i){
        int s = s0 + 16 * mt + 4 * h + i;
        float ga = (float)(n_real - 1 - s);
        bool valid = (s < n_real);
        float v = valid ? __expf(as_[i] - slope0 * ga) : 0.f;
        e_[i] = v; qs_ += v;
      }
      float r = qs_ + __shfl_xor(qs_, 16); r += __shfl_xor(r, 32);
      if (l < 16) atomicAdd(&denl[16 * qt + c], r);
      int q = 16 * qt + c;
      int t0 = 16 * mt + 4 * h;
      uint2 p;
      p.x = (unsigned)f2b(e_[0]) | ((unsigned)f2b(e_[1]) << 16);
      p.y = (unsigned)f2b(e_[2]) | ((unsigned)f2b(e_[3]) << 16);
      *(uint2*)&Pl[q * 32 + (t0 ^ ((q & 1) << 3))] = p;
    }
    bar_lgkm();                          // BAR2: vT/Pl visible; K consumed

    // ---- PV over raw keys: ao[q][e] += P[q][t] * K[t][e] ----
    {
      bf16x8_t Ap0 = *(const bf16x8_t*)&Pl[c * 32 + ((8 * h) ^ ((c & 1) << 3))];
      bf16x8_t Ap1 = *(const bf16x8_t*)&Pl[(16 + c) * 32 + ((8 * h) ^ ((c & 1) << 3))];
      #pragma unroll
      for (int nt = 0; nt < 4; ++nt){
        int e = 64 * w + 16 * nt + c;
        bf16x8_t Bv = *(const bf16x8_t*)&vT[e * 32 + ((8 * h) ^ ((e & 1) << 3))];
        ao[0][nt] = MFMA16(Ap0, Bv, ao[0][nt]);
        ao[1][nt] = MFMA16(Ap1, Bv, ao[1][nt]);
      }
    }
  }

  // ---- accumulate partial numerators / denominators (XCD-local lines after swizzle) ----
  #pragma unroll
  for (int q2 = 0; q2 < 2; ++q2)
    #pragma unroll
    for (int nt = 0; nt < 4; ++nt){
      int e = 64 * w + 16 * nt + c;
      #pragma unroll
      for (int i = 0; i < 4; ++i){
        int q = 16 * q2 + 4 * h + i;
        atomicAdd(&acc[((size_t)b * 32 + q) * 256 + e], ao[q2][nt][i]);
      }
    }
  if (tid < 32) atomicAdd(&deng[b * 32 + tid], denl[tid]);
}

// ---------------- epilogue (IN-PLACE on d_out): out[row][e'] = sum_d (out[row][d]/den[row]) * value_w[e'][d] ----------------
__global__ __launch_bounds__(256) void vproj_norm(
    const float* __restrict__ deng, const unsigned short* __restrict__ wvb,
    float* __restrict__ out){
  __shared__ unsigned short at[64 * 256];
  __shared__ float dl[64];
  int tid = threadIdx.x, w = tid >> 6, l = tid & 63, h = l >> 4, c = l & 15;
  size_t r0 = (size_t)blockIdx.x * 64;
  if (tid < 64) dl[tid] = 1.f / deng[r0 + tid];
  __syncthreads();
  #pragma unroll
  for (int j = 0; j < 16; ++j){
    int idx = j * 256 + tid;
    int row = idx >> 6, c4 = (idx & 63) * 4;
    f32x4_t v = *(const f32x4_t*)(out + (r0 + row) * 256 + c4);
    float iv = dl[row];
    uint2 p;
    p.x = (unsigned)f2b(v[0] * iv) | ((unsigned)f2b(v[1] * iv) << 16);
    p.y = (unsigned)f2b(v[2] * iv) | ((unsigned)f2b(v[3] * iv) << 16);
    *(uint2*)&at[row * 256 + (c4 ^ ((row & 7) << 3))] = p;
  }
  __syncthreads();
  f32x4_t zero4 = {0.f, 0.f, 0.f, 0.f};
  f32x4_t a2[4][4];
  #pragma unroll
  for (int m = 0; m < 4; ++m)
    #pragma unroll
    for (int nt = 0; nt < 4; ++nt) a2[m][nt] = zero4;
  #pragma unroll
  for (int kk = 0; kk < 8; ++kk){
    bf16x8_t A[4];
    #pragma unroll
    for (int m = 0; m < 4; ++m){
      int row = c + 16 * m;
      A[m] = *(const bf16x8_t*)&at[row * 256 + ((kk * 32 + 8 * h) ^ ((row & 7) << 3))];
    }
    #pragma unroll
    for (int nt = 0; nt < 4; ++nt){
      int ep = 64 * w + 16 * nt + c;
      bf16x8_t Bv = *(const bf16x8_t*)(wvb + (size_t)ep * 256 + kk * 32 + 8 * h);
      #pragma unroll
      for (int m = 0; m < 4; ++m) a2[m][nt] = MFMA16(A[m], Bv, a2[m][nt]);
    }
  }
  #pragma unroll
  for (int m = 0; m < 4; ++m)
    #pragma unroll
    for (int nt = 0; nt < 4; ++nt)
      #pragma unroll
      for (int i = 0; i < 4; ++i){
        size_t row = r0 + 16 * m + 4 * h + i;
        int ep = 64 * w + 16 * nt + c;
        out[row * 256 + ep] = a2[m][nt][i];
      }
}

extern "C" void kernel_launch(void* const* d_in, const int* in_sizes, int n_in,
                              void* d_out, int out_size, void* d_ws, size_t ws_size,
                              hipStream_t stream){
  const float* keys    = (const float*)d_in[0];
  const int*   mask    = (const int*)d_in[1];
  const float* context = (const float*)d_in[2];
  const float* queries = (const float*)d_in[3];
  const float* key_w   = (const float*)d_in[4];
  const float* value_w = (const float*)d_in[5];
  const float* logt    = (const float*)d_in[6];
  const float* cond_w  = (const float*)d_in[7];
  const float* cond_b  = (const float*)d_in[8];
  float* out = (float*)d_out;

  unsigned short* wkt = (unsigned short*)d_ws;           // 65536 bf16
  unsigned short* wvb = wkt + 65536;                     // 65536 bf16
  unsigned short* qs  = wvb + 65536;                     // 16384*256 bf16
  unsigned short* qkp = qs + (size_t)16384 * 256;        // 16384*256 bf16
  float* deng = (float*)(qkp + (size_t)16384 * 256);     // 16384 f32
  int*   nreal = (int*)(deng + 16384);                   // 512 int

  hipLaunchKernelGGL(setup_k,  dim3(4480), dim3(256), 0, stream, key_w, value_w, mask,
                     (float4*)out, (float4*)deng, wkt, wvb, nreal);
  hipLaunchKernelGGL(calc_qs,  dim3(2048), dim3(256), 0, stream, context, queries, logt, cond_w, cond_b, qs);
  hipLaunchKernelGGL(calc_qkp, dim3(256), dim3(256), 0, stream, qs, wkt, qkp);
  hipLaunchKernelGGL(attn_part, dim3(1024), dim3(256), 0, stream, keys, nreal, qkp, out, deng);
  hipLaunchKernelGGL(vproj_norm, dim3(256), dim3(256), 0, stream, deng, wvb, out);
}

// Round 19
// 93.655 us; speedup vs baseline: 1.3721x; 1.2369x over previous
//
#include <hip/hip_runtime.h>

typedef short bf16x8_t __attribute__((ext_vector_type(8)));
typedef float f32x4_t  __attribute__((ext_vector_type(4)));

#define MFMA16(a,b,c) __builtin_amdgcn_mfma_f32_16x16x32_bf16(a,b,c,0,0,0)

__device__ __forceinline__ unsigned short f2b(float x){
  unsigned u = __float_as_uint(x);
  u += 0x7fffu + ((u >> 16) & 1u);
  return (unsigned short)(u >> 16);
}

__device__ __forceinline__ void bar_lgkm(){
  asm volatile("s_waitcnt lgkmcnt(0)" ::: "memory");
  __builtin_amdgcn_s_barrier();
  __builtin_amdgcn_sched_barrier(0);
}

// ---------------- setup: weights (0..255) + n_real (256..383). NO zero pass (plain stores now). ----------------
__global__ void setup_k(const float* __restrict__ kw, const float* __restrict__ vw,
                        const int* __restrict__ mask,
                        unsigned short* __restrict__ wktb, unsigned short* __restrict__ wvb,
                        int* __restrict__ nreal){
  int bid = blockIdx.x, tid = threadIdx.x;
  if (bid < 256){
    int i = bid * 256 + tid;                       // 0..65535
    int d = i >> 8, e = i & 255;
    wktb[i] = f2b(kw[e * 256 + d]);                // WkT[d][e] (transposed, for calc_qkp)
    wvb[i]  = f2b(vw[i]);                          // value_w as-is (for vproj_norm)
  } else {
    int b = (bid - 256) * 4 + (tid >> 6), l = tid & 63;
    int s_ = 0;
    #pragma unroll
    for (int j = 0; j < 8; ++j) s_ += mask[(size_t)b * 512 + j * 64 + l];
    #pragma unroll
    for (int k = 1; k < 64; k <<= 1) s_ += __shfl_xor(s_, k);
    if (l == 0) nreal[b] = s_ < 1 ? 1 : (s_ > 512 ? 512 : s_);
  }
}

// ---------------- qs[b*32+q][e] = (queries[q,e] + context[b]@cond_w[q*256+e] + cond_b)*scale*inv_t ----------------
__global__ __launch_bounds__(256) void calc_qs(
    const float* __restrict__ context, const float* __restrict__ queries,
    const float* __restrict__ logt, const float* __restrict__ condw,
    const float* __restrict__ condb, unsigned short* __restrict__ qs){
  __shared__ float ctx_l[8 * 64];
  int tid = threadIdx.x;
  int q   = blockIdx.x & 31;
  int b0  = (blockIdx.x >> 5) * 8;
  int qd  = q * 256 + tid;
  float4 cw[16];
  #pragma unroll
  for (int j = 0; j < 16; ++j) cw[j] = *(const float4*)(condw + (size_t)qd * 64 + 4 * j);
  float qbias = queries[qd] + condb[qd];
  float sc = 0.0625f * __expf(-logt[q >> 2]);      // scale * inv_temperature
  ctx_l[tid]       = context[(size_t)b0 * 64 + tid];
  ctx_l[tid + 256] = context[(size_t)b0 * 64 + tid + 256];
  __syncthreads();
  #pragma unroll
  for (int b = 0; b < 8; ++b){
    const float4* cl = (const float4*)(ctx_l + b * 64);
    float acc = 0.f;
    #pragma unroll
    for (int j = 0; j < 16; ++j){
      float4 cv = cl[j]; float4 w4 = cw[j];
      acc += cv.x * w4.x + cv.y * w4.y + cv.z * w4.z + cv.w * w4.w;
    }
    qs[((size_t)(b0 + b) * 32 + q) * 256 + tid] = f2b((qbias + acc) * sc);
  }
}

// ---------------- qkp[row][d] = sum_e qs[row][e] * key_w[e][d]   (row = b*32+q) ----------------
__global__ __launch_bounds__(256) void calc_qkp(
    const unsigned short* __restrict__ qs, const unsigned short* __restrict__ wkt,
    unsigned short* __restrict__ qkp){
  __shared__ unsigned short at[64 * 256];
  int tid = threadIdx.x, w = tid >> 6, l = tid & 63, h = l >> 4, c = l & 15;
  size_t r0 = (size_t)blockIdx.x * 64;
  #pragma unroll
  for (int j = 0; j < 8; ++j){
    int f = j * 256 + tid;
    int row = f >> 5, col = (f & 31) * 8;
    bf16x8_t v = *(const bf16x8_t*)(qs + (r0 + row) * 256 + col);
    *(bf16x8_t*)&at[row * 256 + (col ^ ((row & 7) << 3))] = v;
  }
  __syncthreads();
  f32x4_t zero4 = {0.f, 0.f, 0.f, 0.f};
  f32x4_t acc[4][4];
  #pragma unroll
  for (int mt = 0; mt < 4; ++mt)
    #pragma unroll
    for (int nt = 0; nt < 4; ++nt) acc[mt][nt] = zero4;
  #pragma unroll
  for (int kk = 0; kk < 8; ++kk){
    bf16x8_t A[4];
    #pragma unroll
    for (int mt = 0; mt < 4; ++mt){
      int row = c + 16 * mt;
      A[mt] = *(const bf16x8_t*)&at[row * 256 + ((kk * 32 + 8 * h) ^ ((row & 7) << 3))];
    }
    #pragma unroll
    for (int nt = 0; nt < 4; ++nt){
      int d = 64 * w + 16 * nt + c;
      bf16x8_t Bv = *(const bf16x8_t*)(wkt + (size_t)d * 256 + kk * 32 + 8 * h);
      #pragma unroll
      for (int mt = 0; mt < 4; ++mt) acc[mt][nt] = MFMA16(A[mt], Bv, acc[mt][nt]);
    }
  }
  #pragma unroll
  for (int mt = 0; mt < 4; ++mt)
    #pragma unroll
    for (int nt = 0; nt < 4; ++nt)
      #pragma unroll
      for (int i = 0; i < 4; ++i){
        size_t row = r0 + 16 * mt + 4 * h + i;
        int d = 64 * w + 16 * nt + c;
        qkp[row * 256 + d] = f2b(acc[mt][nt][i]);
      }
}

// ---------------- attention: ONE block per batch, TILE=64, plain stores (no atomics, no zero) ----------------
// Wave w: logits for row-groups {2(w>>1), 2(w>>1)+1} x q-group (w&1); transpose+PV for e-range 64w..64w+63.
__global__ __launch_bounds__(256, 2) void attn_part(
    const float* __restrict__ keys, const int* __restrict__ nreal,
    const unsigned short* __restrict__ qkp,
    float* __restrict__ out, float* __restrict__ deng){
  __shared__ unsigned short K[64 * 256];   // bf16 keys, swizzled, 32 KB
  __shared__ unsigned short vT[256 * 64];  // K^T [e][t], swizzled, 32 KB
  __shared__ unsigned short Pl[32 * 64];   // P [q][t] bf16, swizzled, 4 KB
  __shared__ float denl[32];

  // XCD swizzle: 512 = 8 x 64; each XCD owns 64 consecutive batches
  int b = (blockIdx.x & 7) * 64 + (blockIdx.x >> 3);
  int n_real = nreal[b];

  int tid = threadIdx.x, w = tid >> 6, l = tid & 63, h = l >> 4, c = l & 15;
  int qg = w & 1, rp = w >> 1;              // q-group, row-pair base (row-groups 2rp, 2rp+1)
  if (tid < 32) denl[tid] = 0.f;

  // identity B-fragments for MFMA-transpose (exact for bf16 inputs)
  bf16x8_t bIe, bIo;
  #pragma unroll
  for (int j = 0; j < 8; ++j){
    bIe[j] = (h == (c >> 3)     && j == (c & 7)) ? (short)0x3F80 : (short)0;
    bIo[j] = (h == 2 + (c >> 3) && j == (c & 7)) ? (short)0x3F80 : (short)0;
  }

  // stage tile 0 into registers (16 x dwordx4 per lane; rows t = 4j + w, cols 4l..4l+3)
  const float* kptr = keys + ((size_t)b * 512 + w) * 256 + 4 * l;
  float4 R[16];
  #pragma unroll
  for (int j = 0; j < 16; ++j) R[j] = *(const float4*)(kptr + j * 1024);

  // this wave's qkp fragments (q-group qg)
  bf16x8_t qf[8];
  #pragma unroll
  for (int kk = 0; kk < 8; ++kk)
    qf[kk] = *(const bf16x8_t*)(qkp + ((size_t)b * 32 + 16 * qg + c) * 256 + kk * 32 + 8 * h);

  float slope0 = exp2f(-2.0f * (float)((c & 3) + 1));   // head = q&3

  f32x4_t zero4 = {0.f, 0.f, 0.f, 0.f};
  f32x4_t ao[2][4];
  #pragma unroll
  for (int q2 = 0; q2 < 2; ++q2)
    #pragma unroll
    for (int nt = 0; nt < 4; ++nt) ao[q2][nt] = zero4;

  int tend = (n_real + 63) >> 6;            // 1..8

  for (int it = 0; it < tend; ++it){
    int s0 = it * 64;
    // ---- convert R -> K (bf16, swizzled); interleave issue of next tile's loads ----
    const float* knext = kptr + (size_t)(it + 1) * (64 * 256);
    #pragma unroll
    for (int j = 0; j < 16; ++j){
      int row = 4 * j + w;
      int d4 = 4 * l;
      float4 kv = R[j];
      if (it + 1 < tend) R[j] = *(const float4*)(knext + j * 1024);
      uint2 p;
      p.x = (unsigned)f2b(kv.x) | ((unsigned)f2b(kv.y) << 16);
      p.y = (unsigned)f2b(kv.z) | ((unsigned)f2b(kv.w) << 16);
      *(uint2*)&K[row * 256 + (d4 ^ ((row & 7) << 3))] = p;
    }
    bar_lgkm();                          // BAR1: K visible; staging loads stay in flight

    // ---- logits (2 row-groups x own q-group) + K^T for e-range 64w (identity MFMA, streamed) ----
    f32x4_t as_[2];
    as_[0] = zero4; as_[1] = zero4;
    #pragma unroll
    for (int kk = 0; kk < 8; ++kk){
      int colk = kk * 32 + 8 * h;
      {
        int r0_ = 16 * (2 * rp) + c, r1_ = 16 * (2 * rp + 1) + c;
        bf16x8_t A0 = *(const bf16x8_t*)&K[r0_ * 256 + (colk ^ ((r0_ & 7) << 3))];
        bf16x8_t A1 = *(const bf16x8_t*)&K[r1_ * 256 + (colk ^ ((r1_ & 7) << 3))];
        as_[0] = MFMA16(A0, qf[kk], as_[0]);
        as_[1] = MFMA16(A1, qf[kk], as_[1]);
      }
      if ((kk >> 1) == w){               // this wave's e-range: kk = 2w, 2w+1
        int ntb = (kk & 1) << 1;
        int e0 = 64 * w + 16 * ntb + c;
        int e1 = e0 + 16;
        #pragma unroll
        for (int g = 0; g < 4; ++g){     // all 4 row-groups -> t = 16g + 4h..
          int rg_ = 16 * g + c;
          bf16x8_t Ag = *(const bf16x8_t*)&K[rg_ * 256 + (colk ^ ((rg_ & 7) << 3))];
          f32x4_t tE = MFMA16(Ag, bIe, zero4);
          f32x4_t tO = MFMA16(Ag, bIo, zero4);
          int t0 = 16 * g + 4 * h;
          uint2 p;
          p.x = (unsigned)f2b(tE[0]) | ((unsigned)f2b(tE[1]) << 16);
          p.y = (unsigned)f2b(tE[2]) | ((unsigned)f2b(tE[3]) << 16);
          *(uint2*)&vT[e0 * 64 + (t0 ^ ((e0 & 7) << 3))] = p;
          p.x = (unsigned)f2b(tO[0]) | ((unsigned)f2b(tO[1]) << 16);
          p.y = (unsigned)f2b(tO[2]) | ((unsigned)f2b(tO[3]) << 16);
          *(uint2*)&vT[e1 * 64 + (t0 ^ ((e1 & 7) << 3))] = p;
        }
      }
    }

    // ---- softmax (fixed-max): P = exp(logit - slope*games_ago), masked -> 0 ----
    {
      float qs_ = 0.f;
      int q = 16 * qg + c;
      #pragma unroll
      for (int g2 = 0; g2 < 2; ++g2){
        int gr = 2 * rp + g2;
        float e_[4];
        #pragma unroll
        for (int i = 0; i < 4; ++i){
          int s = s0 + 16 * gr + 4 * h + i;
          float ga = (float)(n_real - 1 - s);
          bool valid = (s < n_real);
          float v = valid ? __expf(as_[g2][i] - slope0 * ga) : 0.f;
          e_[i] = v; qs_ += v;
        }
        int t0 = 16 * gr + 4 * h;
        uint2 p;
        p.x = (unsigned)f2b(e_[0]) | ((unsigned)f2b(e_[1]) << 16);
        p.y = (unsigned)f2b(e_[2]) | ((unsigned)f2b(e_[3]) << 16);
        *(uint2*)&Pl[q * 64 + (t0 ^ ((q & 7) << 3))] = p;
      }
      float r = qs_ + __shfl_xor(qs_, 16); r += __shfl_xor(r, 32);
      if (l < 16) atomicAdd(&denl[q], r);
    }
    bar_lgkm();                          // BAR2: vT/Pl visible; K consumed

    // ---- PV: ao[q][e] += P[q][t] * K[t][e], t = 64 (2 MFMA k-steps) ----
    #pragma unroll
    for (int ts = 0; ts < 2; ++ts){
      int t0 = 32 * ts + 8 * h;
      bf16x8_t Ap0 = *(const bf16x8_t*)&Pl[c * 64 + (t0 ^ ((c & 7) << 3))];
      bf16x8_t Ap1 = *(const bf16x8_t*)&Pl[(16 + c) * 64 + (t0 ^ (((16 + c) & 7) << 3))];
      #pragma unroll
      for (int nt = 0; nt < 4; ++nt){
        int e = 64 * w + 16 * nt + c;
        bf16x8_t Bv = *(const bf16x8_t*)&vT[e * 64 + (t0 ^ ((e & 7) << 3))];
        ao[0][nt] = MFMA16(Ap0, Bv, ao[0][nt]);
        ao[1][nt] = MFMA16(Ap1, Bv, ao[1][nt]);
      }
    }
  }

  // ---- plain stores (single writer per element): numerators + denominators ----
  #pragma unroll
  for (int q2 = 0; q2 < 2; ++q2)
    #pragma unroll
    for (int nt = 0; nt < 4; ++nt){
      int e = 64 * w + 16 * nt + c;
      #pragma unroll
      for (int i = 0; i < 4; ++i){
        int q = 16 * q2 + 4 * h + i;
        out[((size_t)b * 32 + q) * 256 + e] = ao[q2][nt][i];
      }
    }
  if (tid < 32) deng[b * 32 + tid] = denl[tid];
}

// ---------------- epilogue (IN-PLACE on d_out): out[row][e'] = sum_d (out[row][d]/den[row]) * value_w[e'][d] ----------------
__global__ __launch_bounds__(256) void vproj_norm(
    const float* __restrict__ deng, const unsigned short* __restrict__ wvb,
    float* __restrict__ out){
  __shared__ unsigned short at[64 * 256];
  __shared__ float dl[64];
  int tid = threadIdx.x, w = tid >> 6, l = tid & 63, h = l >> 4, c = l & 15;
  size_t r0 = (size_t)blockIdx.x * 64;
  if (tid < 64) dl[tid] = 1.f / deng[r0 + tid];
  __syncthreads();
  #pragma unroll
  for (int j = 0; j < 16; ++j){
    int idx = j * 256 + tid;
    int row = idx >> 6, c4 = (idx & 63) * 4;
    f32x4_t v = *(const f32x4_t*)(out + (r0 + row) * 256 + c4);
    float iv = dl[row];
    uint2 p;
    p.x = (unsigned)f2b(v[0] * iv) | ((unsigned)f2b(v[1] * iv) << 16);
    p.y = (unsigned)f2b(v[2] * iv) | ((unsigned)f2b(v[3] * iv) << 16);
    *(uint2*)&at[row * 256 + (c4 ^ ((row & 7) << 3))] = p;
  }
  __syncthreads();
  f32x4_t zero4 = {0.f, 0.f, 0.f, 0.f};
  f32x4_t a2[4][4];
  #pragma unroll
  for (int m = 0; m < 4; ++m)
    #pragma unroll
    for (int nt = 0; nt < 4; ++nt) a2[m][nt] = zero4;
  #pragma unroll
  for (int kk = 0; kk < 8; ++kk){
    bf16x8_t A[4];
    #pragma unroll
    for (int m = 0; m < 4; ++m){
      int row = c + 16 * m;
      A[m] = *(const bf16x8_t*)&at[row * 256 + ((kk * 32 + 8 * h) ^ ((row & 7) << 3))];
    }
    #pragma unroll
    for (int nt = 0; nt < 4; ++nt){
      int ep = 64 * w + 16 * nt + c;
      bf16x8_t Bv = *(const bf16x8_t*)(wvb + (size_t)ep * 256 + kk * 32 + 8 * h);
      #pragma unroll
      for (int m = 0; m < 4; ++m) a2[m][nt] = MFMA16(A[m], Bv, a2[m][nt]);
    }
  }
  #pragma unroll
  for (int m = 0; m < 4; ++m)
    #pragma unroll
    for (int nt = 0; nt < 4; ++nt)
      #pragma unroll
      for (int i = 0; i < 4; ++i){
        size_t row = r0 + 16 * m + 4 * h + i;
        int ep = 64 * w + 16 * nt + c;
        out[row * 256 + ep] = a2[m][nt][i];
      }
}

extern "C" void kernel_launch(void* const* d_in, const int* in_sizes, int n_in,
                              void* d_out, int out_size, void* d_ws, size_t ws_size,
                              hipStream_t stream){
  const float* keys    = (const float*)d_in[0];
  const int*   mask    = (const int*)d_in[1];
  const float* context = (const float*)d_in[2];
  const float* queries = (const float*)d_in[3];
  const float* key_w   = (const float*)d_in[4];
  const float* value_w = (const float*)d_in[5];
  const float* logt    = (const float*)d_in[6];
  const float* cond_w  = (const float*)d_in[7];
  const float* cond_b  = (const float*)d_in[8];
  float* out = (float*)d_out;

  unsigned short* wkt = (unsigned short*)d_ws;           // 65536 bf16
  unsigned short* wvb = wkt + 65536;                     // 65536 bf16
  unsigned short* qs  = wvb + 65536;                     // 16384*256 bf16
  unsigned short* qkp = qs + (size_t)16384 * 256;        // 16384*256 bf16
  float* deng = (float*)(qkp + (size_t)16384 * 256);     // 16384 f32
  int*   nreal = (int*)(deng + 16384);                   // 512 int

  hipLaunchKernelGGL(setup_k,  dim3(384), dim3(256), 0, stream, key_w, value_w, mask, wkt, wvb, nreal);
  hipLaunchKernelGGL(calc_qs,  dim3(2048), dim3(256), 0, stream, context, queries, logt, cond_w, cond_b, qs);
  hipLaunchKernelGGL(calc_qkp, dim3(256), dim3(256), 0, stream, qs, wkt, qkp);
  hipLaunchKernelGGL(attn_part, dim3(512), dim3(256), 0, stream, keys, nreal, qkp, out, deng);
  hipLaunchKernelGGL(vproj_norm, dim3(256), dim3(256), 0, stream, deng, wvb, out);
}

// Round 20
// 86.351 us; speedup vs baseline: 1.4881x; 1.0846x over previous
//
#include <hip/hip_runtime.h>

typedef short bf16x8_t __attribute__((ext_vector_type(8)));
typedef float f32x4_t  __attribute__((ext_vector_type(4)));

#define MFMA16(a,b,c) __builtin_amdgcn_mfma_f32_16x16x32_bf16(a,b,c,0,0,0)

__device__ __forceinline__ unsigned short f2b(float x){
  unsigned u = __float_as_uint(x);
  u += 0x7fffu + ((u >> 16) & 1u);
  return (unsigned short)(u >> 16);
}

__device__ __forceinline__ void bar_lgkm(){
  asm volatile("s_waitcnt lgkmcnt(0)" ::: "memory");
  __builtin_amdgcn_s_barrier();
  __builtin_amdgcn_sched_barrier(0);
}

// ---------------- setup: weights (0..255) + n_real (256..383) ----------------
__global__ void setup_k(const float* __restrict__ kw, const float* __restrict__ vw,
                        const int* __restrict__ mask,
                        unsigned short* __restrict__ wktb, unsigned short* __restrict__ wvb,
                        int* __restrict__ nreal){
  int bid = blockIdx.x, tid = threadIdx.x;
  if (bid < 256){
    int i = bid * 256 + tid;                       // 0..65535
    int d = i >> 8, e = i & 255;
    wktb[i] = f2b(kw[e * 256 + d]);                // WkT[d][e] (transposed, for calc_qkp)
    wvb[i]  = f2b(vw[i]);                          // value_w as-is (for fused epilogue)
  } else {
    int b = (bid - 256) * 4 + (tid >> 6), l = tid & 63;
    int s_ = 0;
    #pragma unroll
    for (int j = 0; j < 8; ++j) s_ += mask[(size_t)b * 512 + j * 64 + l];
    #pragma unroll
    for (int k = 1; k < 64; k <<= 1) s_ += __shfl_xor(s_, k);
    if (l == 0) nreal[b] = s_ < 1 ? 1 : (s_ > 512 ? 512 : s_);
  }
}

// ---------------- qs[b*32+q][e] = (queries[q,e] + context[b]@cond_w[q*256+e] + cond_b)*scale*inv_t ----------------
__global__ __launch_bounds__(256) void calc_qs(
    const float* __restrict__ context, const float* __restrict__ queries,
    const float* __restrict__ logt, const float* __restrict__ condw,
    const float* __restrict__ condb, unsigned short* __restrict__ qs){
  __shared__ float ctx_l[8 * 64];
  int tid = threadIdx.x;
  int q   = blockIdx.x & 31;
  int b0  = (blockIdx.x >> 5) * 8;
  int qd  = q * 256 + tid;
  float4 cw[16];
  #pragma unroll
  for (int j = 0; j < 16; ++j) cw[j] = *(const float4*)(condw + (size_t)qd * 64 + 4 * j);
  float qbias = queries[qd] + condb[qd];
  float sc = 0.0625f * __expf(-logt[q >> 2]);      // scale * inv_temperature
  ctx_l[tid]       = context[(size_t)b0 * 64 + tid];
  ctx_l[tid + 256] = context[(size_t)b0 * 64 + tid + 256];
  __syncthreads();
  #pragma unroll
  for (int b = 0; b < 8; ++b){
    const float4* cl = (const float4*)(ctx_l + b * 64);
    float acc = 0.f;
    #pragma unroll
    for (int j = 0; j < 16; ++j){
      float4 cv = cl[j]; float4 w4 = cw[j];
      acc += cv.x * w4.x + cv.y * w4.y + cv.z * w4.z + cv.w * w4.w;
    }
    qs[((size_t)(b0 + b) * 32 + q) * 256 + tid] = f2b((qbias + acc) * sc);
  }
}

// ---------------- qkp[row][d] = sum_e qs[row][e] * key_w[e][d]   (row = b*32+q) ----------------
__global__ __launch_bounds__(256) void calc_qkp(
    const unsigned short* __restrict__ qs, const unsigned short* __restrict__ wkt,
    unsigned short* __restrict__ qkp){
  __shared__ unsigned short at[64 * 256];
  int tid = threadIdx.x, w = tid >> 6, l = tid & 63, h = l >> 4, c = l & 15;
  size_t r0 = (size_t)blockIdx.x * 64;
  #pragma unroll
  for (int j = 0; j < 8; ++j){
    int f = j * 256 + tid;
    int row = f >> 5, col = (f & 31) * 8;
    bf16x8_t v = *(const bf16x8_t*)(qs + (r0 + row) * 256 + col);
    *(bf16x8_t*)&at[row * 256 + (col ^ ((row & 7) << 3))] = v;
  }
  __syncthreads();
  f32x4_t zero4 = {0.f, 0.f, 0.f, 0.f};
  f32x4_t acc[4][4];
  #pragma unroll
  for (int mt = 0; mt < 4; ++mt)
    #pragma unroll
    for (int nt = 0; nt < 4; ++nt) acc[mt][nt] = zero4;
  #pragma unroll
  for (int kk = 0; kk < 8; ++kk){
    bf16x8_t A[4];
    #pragma unroll
    for (int mt = 0; mt < 4; ++mt){
      int row = c + 16 * mt;
      A[mt] = *(const bf16x8_t*)&at[row * 256 + ((kk * 32 + 8 * h) ^ ((row & 7) << 3))];
    }
    #pragma unroll
    for (int nt = 0; nt < 4; ++nt){
      int d = 64 * w + 16 * nt + c;
      bf16x8_t Bv = *(const bf16x8_t*)(wkt + (size_t)d * 256 + kk * 32 + 8 * h);
      #pragma unroll
      for (int mt = 0; mt < 4; ++mt) acc[mt][nt] = MFMA16(A[mt], Bv, acc[mt][nt]);
    }
  }
  #pragma unroll
  for (int mt = 0; mt < 4; ++mt)
    #pragma unroll
    for (int nt = 0; nt < 4; ++nt)
      #pragma unroll
      for (int i = 0; i < 4; ++i){
        size_t row = r0 + 16 * mt + 4 * h + i;
        int d = 64 * w + 16 * nt + c;
        qkp[row * 256 + d] = f2b(acc[mt][nt][i]);
      }
}

// ---------------- attention + FUSED epilogue: one block per batch, TILE=64, final out written here ----------------
// Wave w: logits for row-groups {2(w>>1), 2(w>>1)+1} x q-group (w&1); transpose+PV for e-range 64w..64w+63.
// After the tile loop the block owns the complete numerator+denominator -> normalize, Wv-GEMM, store out.
__global__ __launch_bounds__(256, 2) void attn_part(
    const float* __restrict__ keys, const int* __restrict__ nreal,
    const unsigned short* __restrict__ qkp, const unsigned short* __restrict__ wvb,
    float* __restrict__ out){
  __shared__ unsigned short K[64 * 256];   // bf16 keys, swizzled, 32 KB (reused by epilogue)
  __shared__ unsigned short vT[256 * 64];  // K^T [e][t], swizzled, 32 KB
  __shared__ unsigned short Pl[32 * 64];   // P [q][t] bf16, swizzled, 4 KB
  __shared__ float denl[32];

  // XCD swizzle: 512 = 8 x 64; each XCD owns 64 consecutive batches
  int b = (blockIdx.x & 7) * 64 + (blockIdx.x >> 3);
  int n_real = nreal[b];

  int tid = threadIdx.x, w = tid >> 6, l = tid & 63, h = l >> 4, c = l & 15;
  int qg = w & 1, rp = w >> 1;              // q-group, row-pair base (row-groups 2rp, 2rp+1)
  if (tid < 32) denl[tid] = 0.f;

  // identity B-fragments for MFMA-transpose (exact for bf16 inputs)
  bf16x8_t bIe, bIo;
  #pragma unroll
  for (int j = 0; j < 8; ++j){
    bIe[j] = (h == (c >> 3)     && j == (c & 7)) ? (short)0x3F80 : (short)0;
    bIo[j] = (h == 2 + (c >> 3) && j == (c & 7)) ? (short)0x3F80 : (short)0;
  }

  // stage tile 0 into registers (16 x dwordx4 per lane; rows t = 4j + w, cols 4l..4l+3)
  const float* kptr = keys + ((size_t)b * 512 + w) * 256 + 4 * l;
  float4 R[16];
  #pragma unroll
  for (int j = 0; j < 16; ++j) R[j] = *(const float4*)(kptr + j * 1024);

  // this wave's qkp fragments (q-group qg)
  bf16x8_t qf[8];
  #pragma unroll
  for (int kk = 0; kk < 8; ++kk)
    qf[kk] = *(const bf16x8_t*)(qkp + ((size_t)b * 32 + 16 * qg + c) * 256 + kk * 32 + 8 * h);

  float slope0 = exp2f(-2.0f * (float)((c & 3) + 1));   // head = q&3

  f32x4_t zero4 = {0.f, 0.f, 0.f, 0.f};
  f32x4_t ao[2][4];
  #pragma unroll
  for (int q2 = 0; q2 < 2; ++q2)
    #pragma unroll
    for (int nt = 0; nt < 4; ++nt) ao[q2][nt] = zero4;

  int tend = (n_real + 63) >> 6;            // 1..8

  for (int it = 0; it < tend; ++it){
    int s0 = it * 64;
    // ---- convert R -> K (bf16, swizzled); interleave issue of next tile's loads ----
    const float* knext = kptr + (size_t)(it + 1) * (64 * 256);
    #pragma unroll
    for (int j = 0; j < 16; ++j){
      int row = 4 * j + w;
      int d4 = 4 * l;
      float4 kv = R[j];
      if (it + 1 < tend) R[j] = *(const float4*)(knext + j * 1024);
      uint2 p;
      p.x = (unsigned)f2b(kv.x) | ((unsigned)f2b(kv.y) << 16);
      p.y = (unsigned)f2b(kv.z) | ((unsigned)f2b(kv.w) << 16);
      *(uint2*)&K[row * 256 + (d4 ^ ((row & 7) << 3))] = p;
    }
    bar_lgkm();                          // BAR1: K visible; staging loads stay in flight

    // ---- logits (2 row-groups x own q-group) + K^T for e-range 64w (identity MFMA, streamed) ----
    f32x4_t as_[2];
    as_[0] = zero4; as_[1] = zero4;
    #pragma unroll
    for (int kk = 0; kk < 8; ++kk){
      int colk = kk * 32 + 8 * h;
      {
        int r0_ = 16 * (2 * rp) + c, r1_ = 16 * (2 * rp + 1) + c;
        bf16x8_t A0 = *(const bf16x8_t*)&K[r0_ * 256 + (colk ^ ((r0_ & 7) << 3))];
        bf16x8_t A1 = *(const bf16x8_t*)&K[r1_ * 256 + (colk ^ ((r1_ & 7) << 3))];
        as_[0] = MFMA16(A0, qf[kk], as_[0]);
        as_[1] = MFMA16(A1, qf[kk], as_[1]);
      }
      if ((kk >> 1) == w){               // this wave's e-range: kk = 2w, 2w+1
        int ntb = (kk & 1) << 1;
        int e0 = 64 * w + 16 * ntb + c;
        int e1 = e0 + 16;
        #pragma unroll
        for (int g = 0; g < 4; ++g){     // all 4 row-groups -> t = 16g + 4h..
          int rg_ = 16 * g + c;
          bf16x8_t Ag = *(const bf16x8_t*)&K[rg_ * 256 + (colk ^ ((rg_ & 7) << 3))];
          f32x4_t tE = MFMA16(Ag, bIe, zero4);
          f32x4_t tO = MFMA16(Ag, bIo, zero4);
          int t0 = 16 * g + 4 * h;
          uint2 p;
          p.x = (unsigned)f2b(tE[0]) | ((unsigned)f2b(tE[1]) << 16);
          p.y = (unsigned)f2b(tE[2]) | ((unsigned)f2b(tE[3]) << 16);
          *(uint2*)&vT[e0 * 64 + (t0 ^ ((e0 & 7) << 3))] = p;
          p.x = (unsigned)f2b(tO[0]) | ((unsigned)f2b(tO[1]) << 16);
          p.y = (unsigned)f2b(tO[2]) | ((unsigned)f2b(tO[3]) << 16);
          *(uint2*)&vT[e1 * 64 + (t0 ^ ((e1 & 7) << 3))] = p;
        }
      }
    }

    // ---- softmax (fixed-max): P = exp(logit - slope*games_ago), masked -> 0 ----
    {
      float qs_ = 0.f;
      int q = 16 * qg + c;
      #pragma unroll
      for (int g2 = 0; g2 < 2; ++g2){
        int gr = 2 * rp + g2;
        float e_[4];
        #pragma unroll
        for (int i = 0; i < 4; ++i){
          int s = s0 + 16 * gr + 4 * h + i;
          float ga = (float)(n_real - 1 - s);
          bool valid = (s < n_real);
          float v = valid ? __expf(as_[g2][i] - slope0 * ga) : 0.f;
          e_[i] = v; qs_ += v;
        }
        int t0 = 16 * gr + 4 * h;
        uint2 p;
        p.x = (unsigned)f2b(e_[0]) | ((unsigned)f2b(e_[1]) << 16);
        p.y = (unsigned)f2b(e_[2]) | ((unsigned)f2b(e_[3]) << 16);
        *(uint2*)&Pl[q * 64 + (t0 ^ ((q & 7) << 3))] = p;
      }
      float r = qs_ + __shfl_xor(qs_, 16); r += __shfl_xor(r, 32);
      if (l < 16) atomicAdd(&denl[q], r);
    }
    bar_lgkm();                          // BAR2: vT/Pl visible; K consumed

    // ---- PV: ao[q][e] += P[q][t] * K[t][e], t = 64 (2 MFMA k-steps) ----
    #pragma unroll
    for (int ts = 0; ts < 2; ++ts){
      int t0 = 32 * ts + 8 * h;
      bf16x8_t Ap0 = *(const bf16x8_t*)&Pl[c * 64 + (t0 ^ ((c & 7) << 3))];
      bf16x8_t Ap1 = *(const bf16x8_t*)&Pl[(16 + c) * 64 + (t0 ^ (((16 + c) & 7) << 3))];
      #pragma unroll
      for (int nt = 0; nt < 4; ++nt){
        int e = 64 * w + 16 * nt + c;
        bf16x8_t Bv = *(const bf16x8_t*)&vT[e * 64 + (t0 ^ ((e & 7) << 3))];
        ao[0][nt] = MFMA16(Ap0, Bv, ao[0][nt]);
        ao[1][nt] = MFMA16(Ap1, Bv, ao[1][nt]);
      }
    }
  }

  // ---- FUSED epilogue: out[q][e'] = sum_e (num[q][e]/den[q]) * value_w[e'][e] ----
  // denl complete (all atomicAdds precede last BAR2); K dead -> reuse as the staging tile.
  {
    unsigned short* at = K;              // need 32*256 of the 64*256 buffer
    #pragma unroll
    for (int q2 = 0; q2 < 2; ++q2)
      #pragma unroll
      for (int i = 0; i < 4; ++i){
        int q = 16 * q2 + 4 * h + i;
        float invd = 1.f / denl[q];
        #pragma unroll
        for (int nt = 0; nt < 4; ++nt){
          int e = 64 * w + 16 * nt + c;
          at[q * 256 + (e ^ ((q & 7) << 3))] = f2b(ao[q2][nt][i] * invd);
        }
      }
    __syncthreads();                     // at visible to all waves

    f32x4_t zero4b = {0.f, 0.f, 0.f, 0.f};
    f32x4_t a2[2][4];
    #pragma unroll
    for (int m = 0; m < 2; ++m)
      #pragma unroll
      for (int nt = 0; nt < 4; ++nt) a2[m][nt] = zero4b;
    #pragma unroll
    for (int kk = 0; kk < 8; ++kk){
      bf16x8_t A[2];
      #pragma unroll
      for (int m = 0; m < 2; ++m){
        int row = c + 16 * m;
        A[m] = *(const bf16x8_t*)&at[row * 256 + ((kk * 32 + 8 * h) ^ ((row & 7) << 3))];
      }
      #pragma unroll
      for (int nt = 0; nt < 4; ++nt){
        int ep = 64 * w + 16 * nt + c;
        bf16x8_t Bv = *(const bf16x8_t*)(wvb + (size_t)ep * 256 + kk * 32 + 8 * h);
        #pragma unroll
        for (int m = 0; m < 2; ++m) a2[m][nt] = MFMA16(A[m], Bv, a2[m][nt]);
      }
    }
    #pragma unroll
    for (int m = 0; m < 2; ++m)
      #pragma unroll
      for (int nt = 0; nt < 4; ++nt)
        #pragma unroll
        for (int i = 0; i < 4; ++i){
          int row = 16 * m + 4 * h + i;
          int ep = 64 * w + 16 * nt + c;
          out[((size_t)b * 32 + row) * 256 + ep] = a2[m][nt][i];
        }
  }
}

extern "C" void kernel_launch(void* const* d_in, const int* in_sizes, int n_in,
                              void* d_out, int out_size, void* d_ws, size_t ws_size,
                              hipStream_t stream){
  const float* keys    = (const float*)d_in[0];
  const int*   mask    = (const int*)d_in[1];
  const float* context = (const float*)d_in[2];
  const float* queries = (const float*)d_in[3];
  const float* key_w   = (const float*)d_in[4];
  const float* value_w = (const float*)d_in[5];
  const float* logt    = (const float*)d_in[6];
  const float* cond_w  = (const float*)d_in[7];
  const float* cond_b  = (const float*)d_in[8];
  float* out = (float*)d_out;

  unsigned short* wkt = (unsigned short*)d_ws;           // 65536 bf16
  unsigned short* wvb = wkt + 65536;                     // 65536 bf16
  unsigned short* qs  = wvb + 65536;                     // 16384*256 bf16
  unsigned short* qkp = qs + (size_t)16384 * 256;        // 16384*256 bf16
  int*   nreal = (int*)(qkp + (size_t)16384 * 256);      // 512 int

  hipLaunchKernelGGL(setup_k,  dim3(384), dim3(256), 0, stream, key_w, value_w, mask, wkt, wvb, nreal);
  hipLaunchKernelGGL(calc_qs,  dim3(2048), dim3(256), 0, stream, context, queries, logt, cond_w, cond_b, qs);
  hipLaunchKernelGGL(calc_qkp, dim3(256), dim3(256), 0, stream, qs, wkt, qkp);
  hipLaunchKernelGGL(attn_part, dim3(512), dim3(256), 0, stream, keys, nreal, qkp, wvb, out);
}

// Round 21
// 81.553 us; speedup vs baseline: 1.5757x; 1.0588x over previous
//
#include <hip/hip_runtime.h>

typedef short bf16x8_t __attribute__((ext_vector_type(8)));
typedef float f32x4_t  __attribute__((ext_vector_type(4)));

#define MFMA16(a,b,c) __builtin_amdgcn_mfma_f32_16x16x32_bf16(a,b,c,0,0,0)

__device__ __forceinline__ unsigned short f2b(float x){
  unsigned u = __float_as_uint(x);
  u += 0x7fffu + ((u >> 16) & 1u);
  return (unsigned short)(u >> 16);
}

__device__ __forceinline__ void bar_lgkm(){
  asm volatile("s_waitcnt lgkmcnt(0)" ::: "memory");
  __builtin_amdgcn_s_barrier();
  __builtin_amdgcn_sched_barrier(0);
}

// ---------------- merged: qs (0..2047) | weights->bf16 (2048..2303) | n_real (2304..2431) ----------------
__global__ __launch_bounds__(256) void setup_qs(
    const float* __restrict__ context, const float* __restrict__ queries,
    const float* __restrict__ logt, const float* __restrict__ condw,
    const float* __restrict__ condb,
    const float* __restrict__ kw, const float* __restrict__ vw,
    const int* __restrict__ mask,
    unsigned short* __restrict__ qs,
    unsigned short* __restrict__ wktb, unsigned short* __restrict__ wvb,
    int* __restrict__ nreal){
  int bid = blockIdx.x, tid = threadIdx.x;
  if (bid < 2048){
    __shared__ float ctx_l[8 * 64];
    int q   = bid & 31;
    int b0  = (bid >> 5) * 8;
    int qd  = q * 256 + tid;
    float4 cw[16];
    #pragma unroll
    for (int j = 0; j < 16; ++j) cw[j] = *(const float4*)(condw + (size_t)qd * 64 + 4 * j);
    float qbias = queries[qd] + condb[qd];
    float sc = 0.0625f * __expf(-logt[q >> 2]);      // scale * inv_temperature
    ctx_l[tid]       = context[(size_t)b0 * 64 + tid];
    ctx_l[tid + 256] = context[(size_t)b0 * 64 + tid + 256];
    __syncthreads();
    #pragma unroll
    for (int b = 0; b < 8; ++b){
      const float4* cl = (const float4*)(ctx_l + b * 64);
      float acc = 0.f;
      #pragma unroll
      for (int j = 0; j < 16; ++j){
        float4 cv = cl[j]; float4 w4 = cw[j];
        acc += cv.x * w4.x + cv.y * w4.y + cv.z * w4.z + cv.w * w4.w;
      }
      qs[((size_t)(b0 + b) * 32 + q) * 256 + tid] = f2b((qbias + acc) * sc);
    }
  } else if (bid < 2304){
    int i = (bid - 2048) * 256 + tid;              // 0..65535
    int d = i >> 8, e = i & 255;
    wktb[i] = f2b(kw[e * 256 + d]);                // WkT[d][e] (for fused qkp prologue)
    wvb[i]  = f2b(vw[i]);                          // value_w as-is (for fused epilogue)
  } else {
    int b = (bid - 2304) * 4 + (tid >> 6), l = tid & 63;
    int s_ = 0;
    #pragma unroll
    for (int j = 0; j < 8; ++j) s_ += mask[(size_t)b * 512 + j * 64 + l];
    #pragma unroll
    for (int k = 1; k < 64; k <<= 1) s_ += __shfl_xor(s_, k);
    if (l == 0) nreal[b] = s_ < 1 ? 1 : (s_ > 512 ? 512 : s_);
  }
}

// ---------------- attention, fully fused: qkp-prologue + tiles + Wv epilogue. One block per batch. ----------------
__global__ __launch_bounds__(256, 2) void attn_part(
    const float* __restrict__ keys, const int* __restrict__ nreal,
    const unsigned short* __restrict__ qs, const unsigned short* __restrict__ wkt,
    const unsigned short* __restrict__ wvb, float* __restrict__ out){
  __shared__ unsigned short K[64 * 256];   // bf16 keys, swizzled, 32 KB (reused by epilogue)
  __shared__ unsigned short vT[256 * 64];  // K^T [e][t], swizzled, 32 KB (reused by qkp prologue)
  __shared__ unsigned short Pl[32 * 64];   // P [q][t] bf16, swizzled, 4 KB
  __shared__ float denl[32];

  // XCD swizzle: 512 = 8 x 64; each XCD owns 64 consecutive batches
  int b = (blockIdx.x & 7) * 64 + (blockIdx.x >> 3);
  int n_real = nreal[b];

  int tid = threadIdx.x, w = tid >> 6, l = tid & 63, h = l >> 4, c = l & 15;
  int qg = w & 1, rp = w >> 1;              // q-group, row-pair base (row-groups 2rp, 2rp+1)
  if (tid < 32) denl[tid] = 0.f;

  f32x4_t zero4 = {0.f, 0.f, 0.f, 0.f};

  // identity B-fragments for MFMA-transpose (exact for bf16 inputs)
  bf16x8_t bIe, bIo;
  #pragma unroll
  for (int j = 0; j < 8; ++j){
    bIe[j] = (h == (c >> 3)     && j == (c & 7)) ? (short)0x3F80 : (short)0;
    bIo[j] = (h == 2 + (c >> 3) && j == (c & 7)) ? (short)0x3F80 : (short)0;
  }

  // stage tile 0 into registers (16 x dwordx4 per lane; rows t = 4j + w, cols 4l..4l+3)
  const float* kptr = keys + ((size_t)b * 512 + w) * 256 + 4 * l;
  float4 R[16];
  #pragma unroll
  for (int j = 0; j < 16; ++j) R[j] = *(const float4*)(kptr + j * 1024);

  // ---- fused qkp prologue: qf fragments = (qs[b] @ WkT), computed in-block ----
  // D = WkT-rows (m=d) x qs (n=q): lane c -> q, regs -> d. Fixup d-axis via LDS (vT reused).
  bf16x8_t qf[8];
  {
    unsigned short* qtmp = vT;           // free until tile-0 transpose (post-BAR1)
    f32x4_t qa[4][2];
    #pragma unroll
    for (int mt = 0; mt < 4; ++mt){ qa[mt][0] = zero4; qa[mt][1] = zero4; }
    #pragma unroll
    for (int kk = 0; kk < 8; ++kk){
      int colk = kk * 32 + 8 * h;
      bf16x8_t B0 = *(const bf16x8_t*)(qs + ((size_t)b * 32 + c) * 256 + colk);
      bf16x8_t B1 = *(const bf16x8_t*)(qs + ((size_t)b * 32 + 16 + c) * 256 + colk);
      #pragma unroll
      for (int mt = 0; mt < 4; ++mt){
        int d = 64 * w + 16 * mt + c;
        bf16x8_t Av = *(const bf16x8_t*)(wkt + (size_t)d * 256 + colk);
        qa[mt][0] = MFMA16(Av, B0, qa[mt][0]);
        qa[mt][1] = MFMA16(Av, B1, qa[mt][1]);
      }
    }
    #pragma unroll
    for (int mt = 0; mt < 4; ++mt)
      #pragma unroll
      for (int qt2 = 0; qt2 < 2; ++qt2)
        #pragma unroll
        for (int i = 0; i < 4; ++i){
          int q = 16 * qt2 + c;
          int d = 64 * w + 16 * mt + 4 * h + i;
          qtmp[q * 256 + (d ^ ((q & 7) << 3))] = f2b(qa[mt][qt2][i]);
        }
    bar_lgkm();                          // qtmp visible to all waves (keys loads stay in flight)
    #pragma unroll
    for (int kk = 0; kk < 8; ++kk){
      int q = 16 * qg + c;
      qf[kk] = *(const bf16x8_t*)&qtmp[q * 256 + ((kk * 32 + 8 * h) ^ ((q & 7) << 3))];
    }
    // qf ds_reads complete before each wave's BAR1 arrival (lgkmcnt(0)); vT writes are post-BAR1.
  }

  float slope0 = exp2f(-2.0f * (float)((c & 3) + 1));   // head = q&3

  f32x4_t ao[2][4];
  #pragma unroll
  for (int q2 = 0; q2 < 2; ++q2)
    #pragma unroll
    for (int nt = 0; nt < 4; ++nt) ao[q2][nt] = zero4;

  int tend = (n_real + 63) >> 6;            // 1..8

  for (int it = 0; it < tend; ++it){
    int s0 = it * 64;
    // ---- convert R -> K (bf16, swizzled); interleave issue of next tile's loads ----
    const float* knext = kptr + (size_t)(it + 1) * (64 * 256);
    #pragma unroll
    for (int j = 0; j < 16; ++j){
      int row = 4 * j + w;
      int d4 = 4 * l;
      float4 kv = R[j];
      if (it + 1 < tend) R[j] = *(const float4*)(knext + j * 1024);
      uint2 p;
      p.x = (unsigned)f2b(kv.x) | ((unsigned)f2b(kv.y) << 16);
      p.y = (unsigned)f2b(kv.z) | ((unsigned)f2b(kv.w) << 16);
      *(uint2*)&K[row * 256 + (d4 ^ ((row & 7) << 3))] = p;
    }
    bar_lgkm();                          // BAR1: K visible; staging loads stay in flight

    // ---- logits (2 row-groups x own q-group) + K^T for e-range 64w (identity MFMA, streamed) ----
    f32x4_t as_[2];
    as_[0] = zero4; as_[1] = zero4;
    #pragma unroll
    for (int kk = 0; kk < 8; ++kk){
      int colk = kk * 32 + 8 * h;
      {
        int r0_ = 16 * (2 * rp) + c, r1_ = 16 * (2 * rp + 1) + c;
        bf16x8_t A0 = *(const bf16x8_t*)&K[r0_ * 256 + (colk ^ ((r0_ & 7) << 3))];
        bf16x8_t A1 = *(const bf16x8_t*)&K[r1_ * 256 + (colk ^ ((r1_ & 7) << 3))];
        as_[0] = MFMA16(A0, qf[kk], as_[0]);
        as_[1] = MFMA16(A1, qf[kk], as_[1]);
      }
      if ((kk >> 1) == w){               // this wave's e-range: kk = 2w, 2w+1
        int ntb = (kk & 1) << 1;
        int e0 = 64 * w + 16 * ntb + c;
        int e1 = e0 + 16;
        #pragma unroll
        for (int g = 0; g < 4; ++g){     // all 4 row-groups -> t = 16g + 4h..
          int rg_ = 16 * g + c;
          bf16x8_t Ag = *(const bf16x8_t*)&K[rg_ * 256 + (colk ^ ((rg_ & 7) << 3))];
          f32x4_t tE = MFMA16(Ag, bIe, zero4);
          f32x4_t tO = MFMA16(Ag, bIo, zero4);
          int t0 = 16 * g + 4 * h;
          uint2 p;
          p.x = (unsigned)f2b(tE[0]) | ((unsigned)f2b(tE[1]) << 16);
          p.y = (unsigned)f2b(tE[2]) | ((unsigned)f2b(tE[3]) << 16);
          *(uint2*)&vT[e0 * 64 + (t0 ^ ((e0 & 7) << 3))] = p;
          p.x = (unsigned)f2b(tO[0]) | ((unsigned)f2b(tO[1]) << 16);
          p.y = (unsigned)f2b(tO[2]) | ((unsigned)f2b(tO[3]) << 16);
          *(uint2*)&vT[e1 * 64 + (t0 ^ ((e1 & 7) << 3))] = p;
        }
      }
    }

    // ---- softmax (fixed-max): P = exp(logit - slope*games_ago), masked -> 0 ----
    {
      float qs_ = 0.f;
      int q = 16 * qg + c;
      #pragma unroll
      for (int g2 = 0; g2 < 2; ++g2){
        int gr = 2 * rp + g2;
        float e_[4];
        #pragma unroll
        for (int i = 0; i < 4; ++i){
          int s = s0 + 16 * gr + 4 * h + i;
          float ga = (float)(n_real - 1 - s);
          bool valid = (s < n_real);
          float v = valid ? __expf(as_[g2][i] - slope0 * ga) : 0.f;
          e_[i] = v; qs_ += v;
        }
        int t0 = 16 * gr + 4 * h;
        uint2 p;
        p.x = (unsigned)f2b(e_[0]) | ((unsigned)f2b(e_[1]) << 16);
        p.y = (unsigned)f2b(e_[2]) | ((unsigned)f2b(e_[3]) << 16);
        *(uint2*)&Pl[q * 64 + (t0 ^ ((q & 7) << 3))] = p;
      }
      float r = qs_ + __shfl_xor(qs_, 16); r += __shfl_xor(r, 32);
      if (l < 16) atomicAdd(&denl[q], r);
    }
    bar_lgkm();                          // BAR2: vT/Pl visible; K consumed

    // ---- PV: ao[q][e] += P[q][t] * K[t][e], t = 64 (2 MFMA k-steps) ----
    #pragma unroll
    for (int ts = 0; ts < 2; ++ts){
      int t0 = 32 * ts + 8 * h;
      bf16x8_t Ap0 = *(const bf16x8_t*)&Pl[c * 64 + (t0 ^ ((c & 7) << 3))];
      bf16x8_t Ap1 = *(const bf16x8_t*)&Pl[(16 + c) * 64 + (t0 ^ (((16 + c) & 7) << 3))];
      #pragma unroll
      for (int nt = 0; nt < 4; ++nt){
        int e = 64 * w + 16 * nt + c;
        bf16x8_t Bv = *(const bf16x8_t*)&vT[e * 64 + (t0 ^ ((e & 7) << 3))];
        ao[0][nt] = MFMA16(Ap0, Bv, ao[0][nt]);
        ao[1][nt] = MFMA16(Ap1, Bv, ao[1][nt]);
      }
    }
  }

  // ---- FUSED epilogue: out[q][e'] = sum_e (num[q][e]/den[q]) * value_w[e'][e] ----
  {
    unsigned short* at = K;              // K dead after last tile
    #pragma unroll
    for (int q2 = 0; q2 < 2; ++q2)
      #pragma unroll
      for (int i = 0; i < 4; ++i){
        int q = 16 * q2 + 4 * h + i;
        float invd = 1.f / denl[q];
        #pragma unroll
        for (int nt = 0; nt < 4; ++nt){
          int e = 64 * w + 16 * nt + c;
          at[q * 256 + (e ^ ((q & 7) << 3))] = f2b(ao[q2][nt][i] * invd);
        }
      }
    __syncthreads();                     // at visible to all waves

    f32x4_t a2[2][4];
    #pragma unroll
    for (int m = 0; m < 2; ++m)
      #pragma unroll
      for (int nt = 0; nt < 4; ++nt) a2[m][nt] = zero4;
    #pragma unroll
    for (int kk = 0; kk < 8; ++kk){
      bf16x8_t A[2];
      #pragma unroll
      for (int m = 0; m < 2; ++m){
        int row = c + 16 * m;
        A[m] = *(const bf16x8_t*)&at[row * 256 + ((kk * 32 + 8 * h) ^ ((row & 7) << 3))];
      }
      #pragma unroll
      for (int nt = 0; nt < 4; ++nt){
        int ep = 64 * w + 16 * nt + c;
        bf16x8_t Bv = *(const bf16x8_t*)(wvb + (size_t)ep * 256 + kk * 32 + 8 * h);
        #pragma unroll
        for (int m = 0; m < 2; ++m) a2[m][nt] = MFMA16(A[m], Bv, a2[m][nt]);
      }
    }
    #pragma unroll
    for (int m = 0; m < 2; ++m)
      #pragma unroll
      for (int nt = 0; nt < 4; ++nt)
        #pragma unroll
        for (int i = 0; i < 4; ++i){
          int row = 16 * m + 4 * h + i;
          int ep = 64 * w + 16 * nt + c;
          out[((size_t)b * 32 + row) * 256 + ep] = a2[m][nt][i];
        }
  }
}

extern "C" void kernel_launch(void* const* d_in, const int* in_sizes, int n_in,
                              void* d_out, int out_size, void* d_ws, size_t ws_size,
                              hipStream_t stream){
  const float* keys    = (const float*)d_in[0];
  const int*   mask    = (const int*)d_in[1];
  const float* context = (const float*)d_in[2];
  const float* queries = (const float*)d_in[3];
  const float* key_w   = (const float*)d_in[4];
  const float* value_w = (const float*)d_in[5];
  const float* logt    = (const float*)d_in[6];
  const float* cond_w  = (const float*)d_in[7];
  const float* cond_b  = (const float*)d_in[8];
  float* out = (float*)d_out;

  unsigned short* wkt = (unsigned short*)d_ws;           // 65536 bf16
  unsigned short* wvb = wkt + 65536;                     // 65536 bf16
  unsigned short* qs  = wvb + 65536;                     // 16384*256 bf16
  int*   nreal = (int*)(qs + (size_t)16384 * 256);       // 512 int

  hipLaunchKernelGGL(setup_qs, dim3(2432), dim3(256), 0, stream,
                     context, queries, logt, cond_w, cond_b, key_w, value_w, mask,
                     qs, wkt, wvb, nreal);
  hipLaunchKernelGGL(attn_part, dim3(512), dim3(256), 0, stream, keys, nreal, qs, wkt, wvb, out);
}